// Round 7
// baseline (323.153 us; speedup 1.0000x reference)
//
#include <hip/hip_runtime.h>
#include <hip/hip_fp16.h>
#include <math.h>

#define N_NODES 50000
#define N_EDGES 800000
#define E_TOT (N_EDGES + N_NODES)
#define NB_SCAN ((N_NODES + 255) / 256)
#define N_RT 3125                 // N_NODES / 16 row-tiles

typedef unsigned int uint;
typedef unsigned short ushort;
typedef float f32x4 __attribute__((ext_vector_type(4)));
typedef short v8s __attribute__((ext_vector_type(8)));

__device__ __forceinline__ ushort f2bf(float f) {          // RNE f32->bf16
    uint u = __float_as_uint(f);
    return (ushort)((u + 0x7FFFu + ((u >> 16) & 1u)) >> 16);
}
__device__ __forceinline__ float bf2f(ushort u) {
    return __uint_as_float((uint)u << 16);
}
__device__ __forceinline__ float bflo(uint v) { return __uint_as_float(v << 16); }
__device__ __forceinline__ float bfhi(uint v) { return __uint_as_float(v & 0xFFFF0000u); }

// k-position inside a 32-k block for fragment lane-group g, elem j (consistent A/B)
__device__ __forceinline__ int kmap(int g, int j) {
    return ((j >> 2) << 4) + (g << 2) + (j & 3);
}

// ---------------- CSR build ----------------

__global__ void hist_k(const int* __restrict__ ei, int* __restrict__ cnt) {
    int e = blockIdx.x * blockDim.x + threadIdx.x;
    if (e < N_EDGES)      atomicAdd(&cnt[ei[N_EDGES + e]], 1);
    else if (e < E_TOT)   atomicAdd(&cnt[e - N_EDGES], 1);
}

__global__ __launch_bounds__(256) void scanA_k(const int* __restrict__ cnt,
                                               int* __restrict__ offs,
                                               int* __restrict__ bsum) {
    __shared__ int ws[4];
    int b = blockIdx.x, tid = threadIdx.x;
    int i = b * 256 + tid;
    int v = (i < N_NODES) ? cnt[i] : 0;
    int lane = tid & 63, w = tid >> 6;
    int x = v;
    #pragma unroll
    for (int d = 1; d < 64; d <<= 1) {
        int y = __shfl_up(x, d);
        if (lane >= d) x += y;
    }
    if (lane == 63) ws[w] = x;
    __syncthreads();
    if (tid == 0) {
        int s = 0;
        #pragma unroll
        for (int j = 0; j < 4; j++) { s += ws[j]; ws[j] = s; }
    }
    __syncthreads();
    int incl = x + (w ? ws[w - 1] : 0);
    if (i < N_NODES) offs[i + 1] = incl;
    if (tid == 255) bsum[b] = incl;
}

__global__ __launch_bounds__(256) void scanB_k(const int* __restrict__ bsum,
                                               int* __restrict__ boffs) {
    __shared__ int ws[4];
    int tid = threadIdx.x;
    int v = (tid < NB_SCAN) ? bsum[tid] : 0;
    int lane = tid & 63, w = tid >> 6;
    int x = v;
    #pragma unroll
    for (int d = 1; d < 64; d <<= 1) {
        int y = __shfl_up(x, d);
        if (lane >= d) x += y;
    }
    if (lane == 63) ws[w] = x;
    __syncthreads();
    if (tid == 0) {
        int s = 0;
        #pragma unroll
        for (int j = 0; j < 4; j++) { s += ws[j]; ws[j] = s; }
    }
    __syncthreads();
    int incl = x + (w ? ws[w - 1] : 0);
    if (tid < NB_SCAN) boffs[tid] = incl - v;
}

__global__ __launch_bounds__(256) void scanC_k(const int* __restrict__ boffs,
                                               int* __restrict__ offs,
                                               int* __restrict__ cursor) {
    int b = blockIdx.x;
    int i = b * 256 + threadIdx.x;
    if (i == 0) { offs[0] = 0; cursor[0] = 0; }
    if (i < N_NODES) {
        int v = offs[i + 1] + boffs[b];
        offs[i + 1] = v;
        cursor[i + 1] = v;
    }
}

__global__ void scat_k(const int* __restrict__ ei, int* __restrict__ cursor,
                       int* __restrict__ csr) {
    int e = blockIdx.x * blockDim.x + threadIdx.x;
    int s, d;
    if (e < N_EDGES)      { s = ei[e]; d = ei[N_EDGES + e]; }
    else if (e < E_TOT)   { s = e - N_EDGES; d = s; }
    else return;
    int p = atomicAdd(&cursor[d], 1);
    csr[p] = s;
}

// ---------------- AT[j][k] = sum_d W1[k][h*32+d] * a(j)[d]   (16 x 128 f32) ----

__global__ void w1a_k(const float* __restrict__ W1, const float* __restrict__ a1s,
                      const float* __restrict__ a1d, float* __restrict__ AT) {
    int idx = blockIdx.x * 256 + threadIdx.x;    // 0..2047
    if (idx >= 2048) return;
    int j = idx >> 7, k = idx & 127;
    int h = (j < 8) ? j : j - 8;
    const float* a = (j < 8) ? (a1s + h * 32) : (a1d + h * 32);
    const float* wrow = W1 + (size_t)k * 256 + h * 32;
    float s = 0.f;
    #pragma unroll 8
    for (int d = 0; d < 32; d++) s = fmaf(wrow[d], a[d], s);
    AT[j * 128 + k] = s;
}

// ---------------- W1 -> fragment-packed bf16 [16ct][4ks][64lane][8j] ----------

__global__ void w1f_k(const float* __restrict__ W1, ushort* __restrict__ W1f) {
    int idx = blockIdx.x * 256 + threadIdx.x;    // 0..4095
    if (idx >= 4096) return;
    int lane = idx & 63, ks = (idx >> 6) & 3, ct = idx >> 8;
    int g = lane >> 4, col = ct * 16 + (lane & 15);
    ushort us[8];
    #pragma unroll
    for (int j = 0; j < 8; j++) {
        int k = ks * 32 + kmap(g, j);
        us[j] = f2bf(W1[(size_t)k * 256 + col]);
    }
    uint4 pk;
    pk.x = (uint)us[0] | ((uint)us[1] << 16);
    pk.y = (uint)us[2] | ((uint)us[3] << 16);
    pk.z = (uint)us[4] | ((uint)us[5] << 16);
    pk.w = (uint)us[6] | ((uint)us[7] << 16);
    *((uint4*)(W1f + ((size_t)(ct * 4 + ks) * 64 + lane) * 8)) = pk;
}

// ---------------- prep: x -> frag-packed bf16 + exact f32 scores ----------------

__global__ __launch_bounds__(256) void prep_k(
        const float* __restrict__ x, const float* __restrict__ AT,
        ushort* __restrict__ xbf, float* __restrict__ s1s,
        float* __restrict__ s1d) {
    __shared__ float xs[64][132];
    __shared__ float at[16][132];
    int tid = threadIdx.x;
    int row0 = blockIdx.x * 64;
    for (int i = tid; i < 64 * 32; i += 256) {
        int r = i >> 5, q = i & 31;
        int row = row0 + r; if (row >= N_NODES) row = N_NODES - 1;
        float4 v = ((const float4*)(x + (size_t)row * 128))[q];
        *((float4*)&xs[r][q * 4]) = v;
    }
    for (int i = tid; i < 16 * 32; i += 256) {
        int j = i >> 5, q = i & 31;
        float4 v = ((const float4*)(AT + j * 128))[q];
        *((float4*)&at[j][q * 4]) = v;
    }
    __syncthreads();

    int lane = tid & 63, wv = tid >> 6;
    int rt = blockIdx.x * 4 + wv;
    if (rt < N_RT) {
        int rloc = wv * 16 + (lane & 15);
        int g = lane >> 4;
        #pragma unroll
        for (int ks = 0; ks < 4; ks++) {
            ushort us[8];
            #pragma unroll
            for (int j = 0; j < 8; j++)
                us[j] = f2bf(xs[rloc][ks * 32 + kmap(g, j)]);
            uint4 pk;
            pk.x = (uint)us[0] | ((uint)us[1] << 16);
            pk.y = (uint)us[2] | ((uint)us[3] << 16);
            pk.z = (uint)us[4] | ((uint)us[5] << 16);
            pk.w = (uint)us[6] | ((uint)us[7] << 16);
            *((uint4*)(xbf + (((size_t)rt * 4 + ks) * 64 + lane) * 8)) = pk;
        }
    }

    int row = tid >> 2;
    int jg = tid & 3;
    float acc[4] = {0.f, 0.f, 0.f, 0.f};
    for (int k4 = 0; k4 < 32; k4++) {
        float4 xv = *((float4*)&xs[row][k4 * 4]);
        #pragma unroll
        for (int jq = 0; jq < 4; jq++) {
            int j = jg * 4 + jq;
            float4 av = *((float4*)&at[j][k4 * 4]);
            acc[jq] += xv.x * av.x + xv.y * av.y + xv.z * av.z + xv.w * av.w;
        }
    }
    int grow = row0 + row;
    if (grow < N_NODES) {
        #pragma unroll
        for (int jq = 0; jq < 4; jq++) {
            int j = jg * 4 + jq;
            if (j < 8) s1s[grow * 8 + j] = acc[jq];
            else       s1d[grow * 8 + (j - 8)] = acc[jq];
        }
    }
}

// ---------------- Layer 1 GEMM: bf16 MFMA 16x16x32, 1 row-tile / wave ----------

__global__ __launch_bounds__(256) void gemm1_k(
        const ushort* __restrict__ xbf, const ushort* __restrict__ W1f,
        ushort* __restrict__ h1u) {
    int lane = threadIdx.x & 63, wv = threadIdx.x >> 6;
    int rt = blockIdx.x * 4 + wv;
    if (rt >= N_RT) return;
    f32x4 acc[16];
    #pragma unroll
    for (int ct = 0; ct < 16; ct++) acc[ct] = (f32x4){0.f, 0.f, 0.f, 0.f};
    const v8s* ap = (const v8s*)(xbf) + (size_t)rt * 4 * 64;
    const v8s* bp = (const v8s*)(W1f);
    #pragma unroll
    for (int ks = 0; ks < 4; ks++) {
        v8s a = ap[ks * 64 + lane];
        #pragma unroll
        for (int ct = 0; ct < 16; ct++) {
            v8s b = bp[(ct * 4 + ks) * 64 + lane];
            acc[ct] = __builtin_amdgcn_mfma_f32_16x16x32_bf16(a, b, acc[ct], 0, 0, 0);
        }
    }
    int r0 = rt * 16 + (lane >> 4) * 4;
    int cb = lane & 15;
    #pragma unroll
    for (int ct = 0; ct < 16; ct++) {
        #pragma unroll
        for (int q = 0; q < 4; q++)
            h1u[(size_t)(r0 + q) * 256 + ct * 16 + cb] = f2bf(acc[ct][q]);
    }
}

// ---------------- Layer 1 softmax stats + fp16 alpha materialization ----------

__global__ __launch_bounds__(256) void stats1_k(
        const int* __restrict__ csr, const int* __restrict__ offs,
        const float* __restrict__ s1s, const float* __restrict__ s1d,
        __half* __restrict__ alpha) {
    int n = blockIdx.x * 4 + (threadIdx.x >> 6);
    if (n >= N_NODES) return;
    int lane = threadIdx.x & 63;
    int e8 = lane >> 3, h = lane & 7;
    int beg = offs[n], end = offs[n + 1];
    float sd = s1d[n * 8 + h];
    float m = -3.4e38f, d = 0.f;
    for (int i = beg + e8; i < end; i += 8) {
        int s = csr[i];
        float e = s1s[s * 8 + h] + sd;
        e = (e >= 0.f) ? e : 0.2f * e;
        float mn = fmaxf(m, e);
        d = d * __expf(m - mn) + __expf(e - mn);
        m = mn;
    }
    #pragma unroll
    for (int mask = 8; mask <= 32; mask <<= 1) {
        float om = __shfl_xor(m, mask);
        float od = __shfl_xor(d, mask);
        float nm = fmaxf(m, om);
        d = d * __expf(m - nm) + od * __expf(om - nm);
        m = nm;
    }
    float inv = 1.f / (d + 1e-16f);
    for (int i = beg + e8; i < end; i += 8) {
        int s = csr[i];
        float e = s1s[s * 8 + h] + sd;
        e = (e >= 0.f) ? e : 0.2f * e;
        alpha[(size_t)i * 8 + h] = __float2half(__expf(e - m) * inv);
    }
}

// ---------------- Layer 1 agg + FUSED layer-2 GEMM + scores ----------------
// 4 nodes / block (1 per wave). Gather h1 (bf16) with alpha weights -> f32 row
// in LDS -> h2 = row @ W2 (k split across wave halves) -> h2u bf16 + s2 scores.

__global__ __launch_bounds__(256) void agg1_k(
        const int* __restrict__ csr, const int* __restrict__ offs,
        const ushort* __restrict__ h1u, const __half* __restrict__ alpha,
        const float* __restrict__ b1, const float* __restrict__ W2,
        const float* __restrict__ a2s, const float* __restrict__ a2d,
        ushort* __restrict__ h2u, float* __restrict__ s2s,
        float* __restrict__ s2d) {
    __shared__ float lhr[4][256];
    int lane = threadIdx.x & 63;
    int wv = threadIdx.x >> 6;
    int n = blockIdx.x * 4 + wv;                 // grid exact: no guard
    int h = lane >> 3;
    int beg = offs[n], end = offs[n + 1];
    const uint2* hv = (const uint2*)h1u;
    float acc0 = 0.f, acc1 = 0.f, acc2 = 0.f, acc3 = 0.f;
    int i = beg;
    for (; i + 1 < end; i += 2) {
        int s0 = csr[i], s1 = csr[i + 1];
        float a0 = __half2float(alpha[(size_t)i * 8 + h]);
        float a1 = __half2float(alpha[(size_t)(i + 1) * 8 + h]);
        uint2 v0 = hv[(size_t)s0 * 64 + lane];
        uint2 v1 = hv[(size_t)s1 * 64 + lane];
        acc0 = fmaf(a0, bflo(v0.x), acc0);
        acc1 = fmaf(a0, bfhi(v0.x), acc1);
        acc2 = fmaf(a0, bflo(v0.y), acc2);
        acc3 = fmaf(a0, bfhi(v0.y), acc3);
        acc0 = fmaf(a1, bflo(v1.x), acc0);
        acc1 = fmaf(a1, bfhi(v1.x), acc1);
        acc2 = fmaf(a1, bflo(v1.y), acc2);
        acc3 = fmaf(a1, bfhi(v1.y), acc3);
    }
    if (i < end) {
        int s0 = csr[i];
        float a0 = __half2float(alpha[(size_t)i * 8 + h]);
        uint2 v0 = hv[(size_t)s0 * 64 + lane];
        acc0 = fmaf(a0, bflo(v0.x), acc0);
        acc1 = fmaf(a0, bfhi(v0.x), acc1);
        acc2 = fmaf(a0, bflo(v0.y), acc2);
        acc3 = fmaf(a0, bfhi(v0.y), acc3);
    }
    int c0 = 4 * lane;
    float4 bv = *((const float4*)(b1 + c0));
    float4 o;
    o.x = fmaxf(acc0 + bv.x, 0.f);              // + b1, ReLU
    o.y = fmaxf(acc1 + bv.y, 0.f);
    o.z = fmaxf(acc2 + bv.z, 0.f);
    o.w = fmaxf(acc3 + bv.w, 0.f);
    *((float4*)&lhr[wv][c0]) = o;
    __syncthreads();

    // ---- fused layer-2 GEMM: h2[d] = sum_k lhr[wv][k] * W2[k][d] ----
    int d = lane & 31, half = lane >> 5;
    const float* w2p = W2 + (size_t)half * 128 * 32 + d;
    const float* hrp = &lhr[wv][half * 128];
    float acc = 0.f;
    #pragma unroll 8
    for (int k = 0; k < 128; k++)
        acc = fmaf(hrp[k], w2p[(size_t)k * 32], acc);
    acc += __shfl_xor(acc, 32);                  // combine k-halves
    float ps = acc * a2s[d];
    float pd = acc * a2d[d];
    #pragma unroll
    for (int mask = 1; mask <= 16; mask <<= 1) {
        ps += __shfl_xor(ps, mask);
        pd += __shfl_xor(pd, mask);
    }
    if (lane < 32) h2u[(size_t)n * 32 + d] = f2bf(acc);
    if (lane == 0) { s2s[n] = ps; s2d[n] = pd; }
}

// ---------------- Layer 2: FUSED stats + aggregation ----------------
// 8 nodes / block, 32 lanes / node. Pass 1: online (m,d). Pass 2: edge-parallel
// alpha in registers, shfl-broadcast into the gather FMA.

__global__ __launch_bounds__(256) void agg2_k(
        const int* __restrict__ csr, const int* __restrict__ offs,
        const ushort* __restrict__ h2u, const float* __restrict__ s2s,
        const float* __restrict__ s2d, const float* __restrict__ b2,
        float* __restrict__ out) {
    int l32 = threadIdx.x & 31;
    int n = blockIdx.x * 8 + (threadIdx.x >> 5);   // grid exact: 6250*8=50000
    int beg = offs[n], end = offs[n + 1];
    float sd = s2d[n];
    float m = -3.4e38f, dd = 0.f;
    for (int i = beg + l32; i < end; i += 32) {
        float e = s2s[csr[i]] + sd;
        e = (e >= 0.f) ? e : 0.2f * e;
        float mn = fmaxf(m, e);
        dd = dd * __expf(m - mn) + __expf(e - mn);
        m = mn;
    }
    #pragma unroll
    for (int mask = 1; mask <= 16; mask <<= 1) {
        float om = __shfl_xor(m, mask);
        float od = __shfl_xor(dd, mask);
        float nm = fmaxf(m, om);
        dd = dd * __expf(m - nm) + od * __expf(om - nm);
        m = nm;
    }
    float inv = 1.f / (dd + 1e-16f);
    float acc = 0.f;
    for (int c0 = beg; c0 < end; c0 += 32) {
        int cnt = min(32, end - c0);
        int s = 0; float a = 0.f;
        if (c0 + l32 < end) {
            s = csr[c0 + l32];
            float e = s2s[s] + sd;
            e = (e >= 0.f) ? e : 0.2f * e;
            a = __expf(e - m) * inv;
        }
        for (int e = 0; e < cnt; e++) {
            int se = __shfl(s, e, 32);
            float ae = __shfl(a, e, 32);
            acc = fmaf(ae, bf2f(h2u[(size_t)se * 32 + l32]), acc);
        }
    }
    out[(size_t)n * 32 + l32] = acc + b2[l32];
}

// ---------------- launch ----------------

extern "C" void kernel_launch(void* const* d_in, const int* in_sizes, int n_in,
                              void* d_out, int out_size, void* d_ws, size_t ws_size,
                              hipStream_t stream) {
    const float* x   = (const float*)d_in[0];
    const int*   ei  = (const int*)d_in[1];
    const float* W1  = (const float*)d_in[2];
    const float* a1s = (const float*)d_in[3];
    const float* a1d = (const float*)d_in[4];
    const float* b1  = (const float*)d_in[5];
    const float* W2  = (const float*)d_in[6];
    const float* a2s = (const float*)d_in[7];
    const float* a2d = (const float*)d_in[8];
    const float* b2  = (const float*)d_in[9];
    float* out = (float*)d_out;

    char* w = (char*)d_ws;
    ushort* h1u   = (ushort*)w; w += (size_t)N_NODES * 256 * 2;
    ushort* xbf   = (ushort*)w; w += (size_t)N_RT * 4 * 64 * 8 * 2;
    ushort* W1f   = (ushort*)w; w += (size_t)16 * 4 * 64 * 8 * 2;
    float* AT     = (float*)w;  w += (size_t)16 * 128 * 4;
    ushort* h2u   = (ushort*)w; w += (size_t)N_NODES * 32 * 2;
    float* s1s    = (float*)w;  w += (size_t)N_NODES * 8 * 4;
    float* s1d    = (float*)w;  w += (size_t)N_NODES * 8 * 4;
    float* s2s    = (float*)w;  w += (size_t)N_NODES * 4;
    float* s2d    = (float*)w;  w += (size_t)N_NODES * 4;
    __half* alpha = (__half*)w; w += (size_t)E_TOT * 8 * 2;
    int* cnt    = (int*)w; w += (size_t)N_NODES * 4;
    int* offs   = (int*)w; w += (size_t)(N_NODES + 1) * 4;
    int* cursor = (int*)w; w += (size_t)(N_NODES + 4) * 4;
    int* bsum   = (int*)w; w += (size_t)NB_SCAN * 4;
    int* boffs  = (int*)w; w += (size_t)NB_SCAN * 4;
    int* csr    = (int*)w; w += (size_t)E_TOT * 4;

    hipMemsetAsync(cnt, 0, (size_t)N_NODES * 4, stream);
    hist_k<<<(E_TOT + 255) / 256, 256, 0, stream>>>(ei, cnt);
    scanA_k<<<NB_SCAN, 256, 0, stream>>>(cnt, offs, bsum);
    scanB_k<<<1, 256, 0, stream>>>(bsum, boffs);
    scanC_k<<<NB_SCAN, 256, 0, stream>>>(boffs, offs, cursor);
    scat_k<<<(E_TOT + 255) / 256, 256, 0, stream>>>(ei, cursor, csr);

    w1a_k<<<8, 256, 0, stream>>>(W1, a1s, a1d, AT);
    w1f_k<<<16, 256, 0, stream>>>(W1, W1f);
    prep_k<<<(N_NODES + 63) / 64, 256, 0, stream>>>(x, AT, xbf, s1s, s1d);
    gemm1_k<<<(N_RT + 3) / 4, 256, 0, stream>>>(xbf, W1f, h1u);
    stats1_k<<<(N_NODES + 3) / 4, 256, 0, stream>>>(csr, offs, s1s, s1d, alpha);
    agg1_k<<<N_NODES / 4, 256, 0, stream>>>(csr, offs, h1u, alpha, b1,
                                            W2, a2s, a2d, h2u, s2s, s2d);
    agg2_k<<<N_NODES / 8, 256, 0, stream>>>(csr, offs, h2u, s2s, s2d, b2, out);
}

// Round 8
// 321.971 us; speedup vs baseline: 1.0037x; 1.0037x over previous
//
#include <hip/hip_runtime.h>
#include <hip/hip_fp16.h>
#include <math.h>

#define N_NODES 50000
#define N_EDGES 800000
#define E_TOT (N_EDGES + N_NODES)
#define NB_SCAN ((N_NODES + 255) / 256)
#define N_RT 3125                 // N_NODES / 16 row-tiles

typedef unsigned int uint;
typedef unsigned short ushort;
typedef float f32x4 __attribute__((ext_vector_type(4)));
typedef short v8s __attribute__((ext_vector_type(8)));

__device__ __forceinline__ ushort f2bf(float f) {          // RNE f32->bf16
    uint u = __float_as_uint(f);
    return (ushort)((u + 0x7FFFu + ((u >> 16) & 1u)) >> 16);
}
__device__ __forceinline__ float bf2f(ushort u) {
    return __uint_as_float((uint)u << 16);
}
__device__ __forceinline__ float bflo(uint v) { return __uint_as_float(v << 16); }
__device__ __forceinline__ float bfhi(uint v) { return __uint_as_float(v & 0xFFFF0000u); }

// k-position inside a 32-k block for fragment lane-group g, elem j (consistent A/B)
__device__ __forceinline__ int kmap(int g, int j) {
    return ((j >> 2) << 4) + (g << 2) + (j & 3);
}

// ---------------- CSR build ----------------

__global__ void hist_k(const int* __restrict__ ei, int* __restrict__ cnt) {
    int e = blockIdx.x * blockDim.x + threadIdx.x;
    if (e < N_EDGES)      atomicAdd(&cnt[ei[N_EDGES + e]], 1);
    else if (e < E_TOT)   atomicAdd(&cnt[e - N_EDGES], 1);
}

__global__ __launch_bounds__(256) void scanA_k(const int* __restrict__ cnt,
                                               int* __restrict__ offs,
                                               int* __restrict__ bsum) {
    __shared__ int ws[4];
    int b = blockIdx.x, tid = threadIdx.x;
    int i = b * 256 + tid;
    int v = (i < N_NODES) ? cnt[i] : 0;
    int lane = tid & 63, w = tid >> 6;
    int x = v;
    #pragma unroll
    for (int d = 1; d < 64; d <<= 1) {
        int y = __shfl_up(x, d);
        if (lane >= d) x += y;
    }
    if (lane == 63) ws[w] = x;
    __syncthreads();
    if (tid == 0) {
        int s = 0;
        #pragma unroll
        for (int j = 0; j < 4; j++) { s += ws[j]; ws[j] = s; }
    }
    __syncthreads();
    int incl = x + (w ? ws[w - 1] : 0);
    if (i < N_NODES) offs[i + 1] = incl;
    if (tid == 255) bsum[b] = incl;
}

__global__ __launch_bounds__(256) void scanB_k(const int* __restrict__ bsum,
                                               int* __restrict__ boffs) {
    __shared__ int ws[4];
    int tid = threadIdx.x;
    int v = (tid < NB_SCAN) ? bsum[tid] : 0;
    int lane = tid & 63, w = tid >> 6;
    int x = v;
    #pragma unroll
    for (int d = 1; d < 64; d <<= 1) {
        int y = __shfl_up(x, d);
        if (lane >= d) x += y;
    }
    if (lane == 63) ws[w] = x;
    __syncthreads();
    if (tid == 0) {
        int s = 0;
        #pragma unroll
        for (int j = 0; j < 4; j++) { s += ws[j]; ws[j] = s; }
    }
    __syncthreads();
    int incl = x + (w ? ws[w - 1] : 0);
    if (tid < NB_SCAN) boffs[tid] = incl - v;
}

__global__ __launch_bounds__(256) void scanC_k(const int* __restrict__ boffs,
                                               int* __restrict__ offs,
                                               int* __restrict__ cursor) {
    int b = blockIdx.x;
    int i = b * 256 + threadIdx.x;
    if (i == 0) { offs[0] = 0; cursor[0] = 0; }
    if (i < N_NODES) {
        int v = offs[i + 1] + boffs[b];
        offs[i + 1] = v;
        cursor[i + 1] = v;
    }
}

__global__ void scat_k(const int* __restrict__ ei, int* __restrict__ cursor,
                       int* __restrict__ csr) {
    int e = blockIdx.x * blockDim.x + threadIdx.x;
    int s, d;
    if (e < N_EDGES)      { s = ei[e]; d = ei[N_EDGES + e]; }
    else if (e < E_TOT)   { s = e - N_EDGES; d = s; }
    else return;
    int p = atomicAdd(&cursor[d], 1);
    csr[p] = s;
}

// ---------------- weight prep: AT = W1 @ [a1s|a1d]  +  W1 -> bf16 fragments ----
// blocks 0..7: AT (16x128 f32). blocks 8..23: W1f [16ct][4ks][64lane][8j].

__global__ void wprep_k(const float* __restrict__ W1, const float* __restrict__ a1s,
                        const float* __restrict__ a1d, float* __restrict__ AT,
                        ushort* __restrict__ W1f) {
    if (blockIdx.x < 8) {
        int idx = blockIdx.x * 256 + threadIdx.x;    // 0..2047
        int j = idx >> 7, k = idx & 127;
        int h = (j < 8) ? j : j - 8;
        const float* a = (j < 8) ? (a1s + h * 32) : (a1d + h * 32);
        const float* wrow = W1 + (size_t)k * 256 + h * 32;
        float s = 0.f;
        #pragma unroll 8
        for (int d = 0; d < 32; d++) s = fmaf(wrow[d], a[d], s);
        AT[j * 128 + k] = s;
    } else {
        int idx = (blockIdx.x - 8) * 256 + threadIdx.x;   // 0..4095
        int lane = idx & 63, ks = (idx >> 6) & 3, ct = idx >> 8;
        int g = lane >> 4, col = ct * 16 + (lane & 15);
        ushort us[8];
        #pragma unroll
        for (int j = 0; j < 8; j++) {
            int k = ks * 32 + kmap(g, j);
            us[j] = f2bf(W1[(size_t)k * 256 + col]);
        }
        uint4 pk;
        pk.x = (uint)us[0] | ((uint)us[1] << 16);
        pk.y = (uint)us[2] | ((uint)us[3] << 16);
        pk.z = (uint)us[4] | ((uint)us[5] << 16);
        pk.w = (uint)us[6] | ((uint)us[7] << 16);
        *((uint4*)(W1f + ((size_t)(ct * 4 + ks) * 64 + lane) * 8)) = pk;
    }
}

// ---------------- fused prep + layer-1 MFMA GEMM + exact f32 scores ----------
// 64 rows / block, 1 row-tile (16 rows) / wave. x tile staged in LDS; A-frags
// packed in registers; h1 stored via LDS transpose as coalesced uint4.

__global__ __launch_bounds__(256) void fgemm1_k(
        const float* __restrict__ x, const float* __restrict__ AT,
        const ushort* __restrict__ W1f, ushort* __restrict__ h1u,
        float* __restrict__ s1s, float* __restrict__ s1d) {
    __shared__ float xs[64][132];      // 33.8 KB; reused as bf16 transpose buf
    __shared__ float at[16][132];      // 8.4 KB
    int tid = threadIdx.x;
    int row0 = blockIdx.x * 64;
    for (int i = tid; i < 64 * 32; i += 256) {
        int r = i >> 5, q = i & 31;
        int row = row0 + r; if (row >= N_NODES) row = N_NODES - 1;
        float4 v = ((const float4*)(x + (size_t)row * 128))[q];
        *((float4*)&xs[r][q * 4]) = v;
    }
    for (int i = tid; i < 16 * 32; i += 256) {
        int j = i >> 5, q = i & 31;
        float4 v = ((const float4*)(AT + j * 128))[q];
        *((float4*)&at[j][q * 4]) = v;
    }
    __syncthreads();

    // ---- exact f32 scores: row = tid>>2, 4 of 16 score cols per thread ----
    {
        int row = tid >> 2, jg = tid & 3;
        float acc[4] = {0.f, 0.f, 0.f, 0.f};
        for (int k4 = 0; k4 < 32; k4++) {
            float4 xv = *((float4*)&xs[row][k4 * 4]);
            #pragma unroll
            for (int jq = 0; jq < 4; jq++) {
                int j = jg * 4 + jq;
                float4 av = *((float4*)&at[j][k4 * 4]);
                acc[jq] += xv.x * av.x + xv.y * av.y + xv.z * av.z + xv.w * av.w;
            }
        }
        int grow = row0 + row;
        if (grow < N_NODES) {
            #pragma unroll
            for (int jq = 0; jq < 4; jq++) {
                int j = jg * 4 + jq;
                if (j < 8) s1s[grow * 8 + j] = acc[jq];
                else       s1d[grow * 8 + (j - 8)] = acc[jq];
            }
        }
    }

    // ---- pack A-fragments into registers from LDS x tile ----
    int lane = tid & 63, wv = tid >> 6;
    int rt = blockIdx.x * 4 + wv;
    int rloc = wv * 16 + (lane & 15);
    int g = lane >> 4;
    v8s afr[4];
    #pragma unroll
    for (int ks = 0; ks < 4; ks++) {
        ushort us[8];
        #pragma unroll
        for (int j = 0; j < 8; j++)
            us[j] = f2bf(xs[rloc][ks * 32 + kmap(g, j)]);
        uint4 pk;
        pk.x = (uint)us[0] | ((uint)us[1] << 16);
        pk.y = (uint)us[2] | ((uint)us[3] << 16);
        pk.z = (uint)us[4] | ((uint)us[5] << 16);
        pk.w = (uint)us[6] | ((uint)us[7] << 16);
        afr[ks] = *((v8s*)&pk);
    }
    __syncthreads();   // all xs/at reads done; xs becomes transpose buffer

    // ---- MFMA: 64 x (16x16x32) per wave ----
    f32x4 acc[16];
    #pragma unroll
    for (int ct = 0; ct < 16; ct++) acc[ct] = (f32x4){0.f, 0.f, 0.f, 0.f};
    const v8s* bp = (const v8s*)(W1f);
    #pragma unroll
    for (int ks = 0; ks < 4; ks++) {
        #pragma unroll
        for (int ct = 0; ct < 16; ct++) {
            v8s b = bp[(ct * 4 + ks) * 64 + lane];
            acc[ct] = __builtin_amdgcn_mfma_f32_16x16x32_bf16(afr[ks], b, acc[ct], 0, 0, 0);
        }
    }

    // ---- bf16 + LDS transpose (row stride 264 ushort) + coalesced store ----
    if (rt < N_RT) {
        ushort* tb = ((ushort*)&xs[0][0]) + wv * 16 * 264;
        int lr = lane >> 4, cb = lane & 15;
        #pragma unroll
        for (int ct = 0; ct < 16; ct++) {
            #pragma unroll
            for (int q = 0; q < 4; q++)
                tb[(lr * 4 + q) * 264 + ct * 16 + cb] = f2bf(acc[ct][q]);
        }
        // wave-local: LDS writes then reads by same wave (HW waits via lgkmcnt)
        #pragma unroll
        for (int j = 0; j < 8; j++) {
            int idx = j * 64 + lane;             // 512 uint4 per wave tile
            int rl = idx >> 5, cu = idx & 31;
            uint4 v = *((uint4*)&tb[rl * 264 + cu * 8]);
            ((uint4*)(h1u + (size_t)(rt * 16 + rl) * 256))[cu] = v;
        }
    }
}

// ---------------- Layer 1 softmax stats + fp16 alpha materialization ----------

__global__ __launch_bounds__(256) void stats1_k(
        const int* __restrict__ csr, const int* __restrict__ offs,
        const float* __restrict__ s1s, const float* __restrict__ s1d,
        __half* __restrict__ alpha) {
    int n = blockIdx.x * 4 + (threadIdx.x >> 6);
    if (n >= N_NODES) return;
    int lane = threadIdx.x & 63;
    int e8 = lane >> 3, h = lane & 7;
    int beg = offs[n], end = offs[n + 1];
    float sd = s1d[n * 8 + h];
    float m = -3.4e38f, d = 0.f;
    for (int i = beg + e8; i < end; i += 8) {
        int s = csr[i];
        float e = s1s[s * 8 + h] + sd;
        e = (e >= 0.f) ? e : 0.2f * e;
        float mn = fmaxf(m, e);
        d = d * __expf(m - mn) + __expf(e - mn);
        m = mn;
    }
    #pragma unroll
    for (int mask = 8; mask <= 32; mask <<= 1) {
        float om = __shfl_xor(m, mask);
        float od = __shfl_xor(d, mask);
        float nm = fmaxf(m, om);
        d = d * __expf(m - nm) + od * __expf(om - nm);
        m = nm;
    }
    float inv = 1.f / (d + 1e-16f);
    for (int i = beg + e8; i < end; i += 8) {
        int s = csr[i];
        float e = s1s[s * 8 + h] + sd;
        e = (e >= 0.f) ? e : 0.2f * e;
        alpha[(size_t)i * 8 + h] = __float2half(__expf(e - m) * inv);
    }
}

// ---------------- Layer 1 aggregation: pure bf16 gather ----------------
// 4 nodes / block, 64 lanes / node, 4 channels (uint2) / lane.

__global__ __launch_bounds__(256) void agg1_k(
        const int* __restrict__ csr, const int* __restrict__ offs,
        const ushort* __restrict__ h1u, const __half* __restrict__ alpha,
        const float* __restrict__ b1, float* __restrict__ hr) {
    int lane = threadIdx.x & 63;
    int n = blockIdx.x * 4 + (threadIdx.x >> 6);
    int h = lane >> 3;
    int beg = offs[n], end = offs[n + 1];
    const uint2* hv = (const uint2*)h1u;
    float acc0 = 0.f, acc1 = 0.f, acc2 = 0.f, acc3 = 0.f;
    int i = beg;
    for (; i + 1 < end; i += 2) {
        int s0 = csr[i], s1 = csr[i + 1];
        float a0 = __half2float(alpha[(size_t)i * 8 + h]);
        float a1 = __half2float(alpha[(size_t)(i + 1) * 8 + h]);
        uint2 v0 = hv[(size_t)s0 * 64 + lane];
        uint2 v1 = hv[(size_t)s1 * 64 + lane];
        acc0 = fmaf(a0, bflo(v0.x), acc0);
        acc1 = fmaf(a0, bfhi(v0.x), acc1);
        acc2 = fmaf(a0, bflo(v0.y), acc2);
        acc3 = fmaf(a0, bfhi(v0.y), acc3);
        acc0 = fmaf(a1, bflo(v1.x), acc0);
        acc1 = fmaf(a1, bfhi(v1.x), acc1);
        acc2 = fmaf(a1, bflo(v1.y), acc2);
        acc3 = fmaf(a1, bfhi(v1.y), acc3);
    }
    if (i < end) {
        int s0 = csr[i];
        float a0 = __half2float(alpha[(size_t)i * 8 + h]);
        uint2 v0 = hv[(size_t)s0 * 64 + lane];
        acc0 = fmaf(a0, bflo(v0.x), acc0);
        acc1 = fmaf(a0, bfhi(v0.x), acc1);
        acc2 = fmaf(a0, bflo(v0.y), acc2);
        acc3 = fmaf(a0, bfhi(v0.y), acc3);
    }
    int c0 = 4 * lane;
    float4 bv = *((const float4*)(b1 + c0));
    float4 o;
    o.x = fmaxf(acc0 + bv.x, 0.f);
    o.y = fmaxf(acc1 + bv.y, 0.f);
    o.z = fmaxf(acc2 + bv.z, 0.f);
    o.w = fmaxf(acc3 + bv.w, 0.f);
    ((float4*)hr)[(size_t)n * 64 + lane] = o;    // + b1, ReLU
}

// ---------------- Layer 2 GEMM (32-row tile, 4x1 per thread, LDS broadcast) --

__global__ __launch_bounds__(256) void gemm2_k(
        const float* __restrict__ hr, const float* __restrict__ W2,
        const float* __restrict__ a2s, const float* __restrict__ a2d,
        ushort* __restrict__ h2u, float* __restrict__ s2s,
        float* __restrict__ s2d) {
    __shared__ float hs[32][256];
    int tid = threadIdx.x;
    int row0 = blockIdx.x * 32;
    for (int i = tid; i < 32 * 64; i += 256) {
        int r = i >> 6, q = i & 63;
        int row = row0 + r; if (row >= N_NODES) row = N_NODES - 1;
        float4 v = ((const float4*)(hr + (size_t)row * 256))[q];
        *((float4*)&hs[r][q * 4]) = v;
    }
    __syncthreads();
    int c = tid & 31, g = tid >> 5;
    float acc[4] = {0.f, 0.f, 0.f, 0.f};
    for (int k = 0; k < 256; k += 4) {
        float w0 = W2[(size_t)(k + 0) * 32 + c];
        float w1 = W2[(size_t)(k + 1) * 32 + c];
        float w2 = W2[(size_t)(k + 2) * 32 + c];
        float w3 = W2[(size_t)(k + 3) * 32 + c];
        #pragma unroll
        for (int r = 0; r < 4; r++) {
            float4 xv = *((const float4*)&hs[g * 4 + r][k]);
            acc[r] = fmaf(xv.x, w0, acc[r]);
            acc[r] = fmaf(xv.y, w1, acc[r]);
            acc[r] = fmaf(xv.z, w2, acc[r]);
            acc[r] = fmaf(xv.w, w3, acc[r]);
        }
    }
    float av_s = a2s[c], av_d = a2d[c];
    #pragma unroll
    for (int r = 0; r < 4; r++) {
        int row = row0 + g * 4 + r;
        float ps = acc[r] * av_s, pd = acc[r] * av_d;
        #pragma unroll
        for (int mask = 16; mask >= 1; mask >>= 1) {
            ps += __shfl_xor(ps, mask);
            pd += __shfl_xor(pd, mask);
        }
        if (row < N_NODES) {
            h2u[(size_t)row * 32 + c] = f2bf(acc[r]);
            if (c == 0) { s2s[row] = ps; s2d[row] = pd; }
        }
    }
}

// ---------------- Layer 2: FUSED stats + aggregation ----------------
// 8 nodes / block, 32 lanes / node.

__global__ __launch_bounds__(256) void agg2_k(
        const int* __restrict__ csr, const int* __restrict__ offs,
        const ushort* __restrict__ h2u, const float* __restrict__ s2s,
        const float* __restrict__ s2d, const float* __restrict__ b2,
        float* __restrict__ out) {
    int l32 = threadIdx.x & 31;
    int n = blockIdx.x * 8 + (threadIdx.x >> 5);   // grid exact: 6250*8=50000
    int beg = offs[n], end = offs[n + 1];
    float sd = s2d[n];
    float m = -3.4e38f, dd = 0.f;
    for (int i = beg + l32; i < end; i += 32) {
        float e = s2s[csr[i]] + sd;
        e = (e >= 0.f) ? e : 0.2f * e;
        float mn = fmaxf(m, e);
        dd = dd * __expf(m - mn) + __expf(e - mn);
        m = mn;
    }
    #pragma unroll
    for (int mask = 1; mask <= 16; mask <<= 1) {
        float om = __shfl_xor(m, mask);
        float od = __shfl_xor(dd, mask);
        float nm = fmaxf(m, om);
        dd = dd * __expf(m - nm) + od * __expf(om - nm);
        m = nm;
    }
    float inv = 1.f / (dd + 1e-16f);
    float acc = 0.f;
    for (int c0 = beg; c0 < end; c0 += 32) {
        int cnt = min(32, end - c0);
        int s = 0; float a = 0.f;
        if (c0 + l32 < end) {
            s = csr[c0 + l32];
            float e = s2s[s] + sd;
            e = (e >= 0.f) ? e : 0.2f * e;
            a = __expf(e - m) * inv;
        }
        for (int e = 0; e < cnt; e++) {
            int se = __shfl(s, e, 32);
            float ae = __shfl(a, e, 32);
            acc = fmaf(ae, bf2f(h2u[(size_t)se * 32 + l32]), acc);
        }
    }
    out[(size_t)n * 32 + l32] = acc + b2[l32];
}

// ---------------- launch ----------------

extern "C" void kernel_launch(void* const* d_in, const int* in_sizes, int n_in,
                              void* d_out, int out_size, void* d_ws, size_t ws_size,
                              hipStream_t stream) {
    const float* x   = (const float*)d_in[0];
    const int*   ei  = (const int*)d_in[1];
    const float* W1  = (const float*)d_in[2];
    const float* a1s = (const float*)d_in[3];
    const float* a1d = (const float*)d_in[4];
    const float* b1  = (const float*)d_in[5];
    const float* W2  = (const float*)d_in[6];
    const float* a2s = (const float*)d_in[7];
    const float* a2d = (const float*)d_in[8];
    const float* b2  = (const float*)d_in[9];
    float* out = (float*)d_out;

    char* w = (char*)d_ws;
    float* hr     = (float*)w;  w += (size_t)N_NODES * 256 * 4;
    ushort* h1u   = (ushort*)w; w += (size_t)N_NODES * 256 * 2;
    ushort* W1f   = (ushort*)w; w += (size_t)16 * 4 * 64 * 8 * 2;
    float* AT     = (float*)w;  w += (size_t)16 * 128 * 4;
    ushort* h2u   = (ushort*)w; w += (size_t)N_NODES * 32 * 2;
    float* s1s    = (float*)w;  w += (size_t)N_NODES * 8 * 4;
    float* s1d    = (float*)w;  w += (size_t)N_NODES * 8 * 4;
    float* s2s    = (float*)w;  w += (size_t)N_NODES * 4;
    float* s2d    = (float*)w;  w += (size_t)N_NODES * 4;
    __half* alpha = (__half*)w; w += (size_t)E_TOT * 8 * 2;
    int* cnt    = (int*)w; w += (size_t)N_NODES * 4;
    int* offs   = (int*)w; w += (size_t)(N_NODES + 1) * 4;
    int* cursor = (int*)w; w += (size_t)(N_NODES + 4) * 4;
    int* bsum   = (int*)w; w += (size_t)NB_SCAN * 4;
    int* boffs  = (int*)w; w += (size_t)NB_SCAN * 4;
    int* csr    = (int*)w; w += (size_t)E_TOT * 4;

    hipMemsetAsync(cnt, 0, (size_t)N_NODES * 4, stream);
    hist_k<<<(E_TOT + 255) / 256, 256, 0, stream>>>(ei, cnt);
    scanA_k<<<NB_SCAN, 256, 0, stream>>>(cnt, offs, bsum);
    scanB_k<<<1, 256, 0, stream>>>(bsum, boffs);
    scanC_k<<<NB_SCAN, 256, 0, stream>>>(boffs, offs, cursor);
    scat_k<<<(E_TOT + 255) / 256, 256, 0, stream>>>(ei, cursor, csr);

    wprep_k<<<24, 256, 0, stream>>>(W1, a1s, a1d, AT, W1f);
    fgemm1_k<<<(N_NODES + 63) / 64, 256, 0, stream>>>(x, AT, W1f, h1u, s1s, s1d);
    stats1_k<<<(N_NODES + 3) / 4, 256, 0, stream>>>(csr, offs, s1s, s1d, alpha);
    agg1_k<<<N_NODES / 4, 256, 0, stream>>>(csr, offs, h1u, alpha, b1, hr);
    gemm2_k<<<(N_NODES + 31) / 32, 256, 0, stream>>>(hr, W2, a2s, a2d, h2u, s2s, s2d);
    agg2_k<<<N_NODES / 8, 256, 0, stream>>>(csr, offs, h2u, s2s, s2d, b2, out);
}

// Round 9
// 304.391 us; speedup vs baseline: 1.0616x; 1.0578x over previous
//
#include <hip/hip_runtime.h>
#include <hip/hip_fp16.h>
#include <math.h>

#define N_NODES 50000
#define N_EDGES 800000
#define E_TOT (N_EDGES + N_NODES)
#define NB_SCAN ((N_NODES + 255) / 256)
#define N_RT 3125                 // N_NODES / 16 row-tiles (exact)

typedef unsigned int uint;
typedef unsigned short ushort;
typedef float f32x4 __attribute__((ext_vector_type(4)));
typedef short v8s __attribute__((ext_vector_type(8)));

__device__ __forceinline__ ushort f2bf(float f) {          // RNE f32->bf16
    uint u = __float_as_uint(f);
    return (ushort)((u + 0x7FFFu + ((u >> 16) & 1u)) >> 16);
}
__device__ __forceinline__ float bf2f(ushort u) {
    return __uint_as_float((uint)u << 16);
}
__device__ __forceinline__ float bflo(uint v) { return __uint_as_float(v << 16); }
__device__ __forceinline__ float bfhi(uint v) { return __uint_as_float(v & 0xFFFF0000u); }

// k-position inside a 32-k block for fragment lane-group g, elem j (consistent A/B)
__device__ __forceinline__ int kmap(int g, int j) {
    return ((j >> 2) << 4) + (g << 2) + (j & 3);
}

// ---------------- CSR build ----------------

__global__ void hist_k(const int* __restrict__ ei, int* __restrict__ cnt) {
    int e = blockIdx.x * blockDim.x + threadIdx.x;
    if (e < N_EDGES)      atomicAdd(&cnt[ei[N_EDGES + e]], 1);
    else if (e < E_TOT)   atomicAdd(&cnt[e - N_EDGES], 1);
}

__global__ __launch_bounds__(256) void scanA_k(const int* __restrict__ cnt,
                                               int* __restrict__ offs,
                                               int* __restrict__ bsum) {
    __shared__ int ws[4];
    int b = blockIdx.x, tid = threadIdx.x;
    int i = b * 256 + tid;
    int v = (i < N_NODES) ? cnt[i] : 0;
    int lane = tid & 63, w = tid >> 6;
    int x = v;
    #pragma unroll
    for (int d = 1; d < 64; d <<= 1) {
        int y = __shfl_up(x, d);
        if (lane >= d) x += y;
    }
    if (lane == 63) ws[w] = x;
    __syncthreads();
    if (tid == 0) {
        int s = 0;
        #pragma unroll
        for (int j = 0; j < 4; j++) { s += ws[j]; ws[j] = s; }
    }
    __syncthreads();
    int incl = x + (w ? ws[w - 1] : 0);
    if (i < N_NODES) offs[i + 1] = incl;
    if (tid == 255) bsum[b] = incl;
}

__global__ __launch_bounds__(256) void scanB_k(const int* __restrict__ bsum,
                                               int* __restrict__ boffs) {
    __shared__ int ws[4];
    int tid = threadIdx.x;
    int v = (tid < NB_SCAN) ? bsum[tid] : 0;
    int lane = tid & 63, w = tid >> 6;
    int x = v;
    #pragma unroll
    for (int d = 1; d < 64; d <<= 1) {
        int y = __shfl_up(x, d);
        if (lane >= d) x += y;
    }
    if (lane == 63) ws[w] = x;
    __syncthreads();
    if (tid == 0) {
        int s = 0;
        #pragma unroll
        for (int j = 0; j < 4; j++) { s += ws[j]; ws[j] = s; }
    }
    __syncthreads();
    int incl = x + (w ? ws[w - 1] : 0);
    if (tid < NB_SCAN) boffs[tid] = incl - v;
}

__global__ __launch_bounds__(256) void scanC_k(const int* __restrict__ boffs,
                                               int* __restrict__ offs,
                                               int* __restrict__ cursor) {
    int b = blockIdx.x;
    int i = b * 256 + threadIdx.x;
    if (i == 0) { offs[0] = 0; cursor[0] = 0; }
    if (i < N_NODES) {
        int v = offs[i + 1] + boffs[b];
        offs[i + 1] = v;
        cursor[i + 1] = v;
    }
}

__global__ void scat_k(const int* __restrict__ ei, int* __restrict__ cursor,
                       int* __restrict__ csr) {
    int e = blockIdx.x * blockDim.x + threadIdx.x;
    int s, d;
    if (e < N_EDGES)      { s = ei[e]; d = ei[N_EDGES + e]; }
    else if (e < E_TOT)   { s = e - N_EDGES; d = s; }
    else return;
    int p = atomicAdd(&cursor[d], 1);
    csr[p] = s;
}

// ---------------- weight prep: AT = W1 @ [a1s|a1d]  +  W1 -> bf16 fragments ----
// blocks 0..7: AT (16x128 f32). blocks 8..23: W1f [16ct][4ks][64lane][8j].

__global__ void wprep_k(const float* __restrict__ W1, const float* __restrict__ a1s,
                        const float* __restrict__ a1d, float* __restrict__ AT,
                        ushort* __restrict__ W1f) {
    if (blockIdx.x < 8) {
        int idx = blockIdx.x * 256 + threadIdx.x;    // 0..2047
        int j = idx >> 7, k = idx & 127;
        int h = (j < 8) ? j : j - 8;
        const float* a = (j < 8) ? (a1s + h * 32) : (a1d + h * 32);
        const float* wrow = W1 + (size_t)k * 256 + h * 32;
        float s = 0.f;
        #pragma unroll 8
        for (int d = 0; d < 32; d++) s = fmaf(wrow[d], a[d], s);
        AT[j * 128 + k] = s;
    } else {
        int idx = (blockIdx.x - 8) * 256 + threadIdx.x;   // 0..4095
        int lane = idx & 63, ks = (idx >> 6) & 3, ct = idx >> 8;
        int g = lane >> 4, col = ct * 16 + (lane & 15);
        ushort us[8];
        #pragma unroll
        for (int j = 0; j < 8; j++) {
            int k = ks * 32 + kmap(g, j);
            us[j] = f2bf(W1[(size_t)k * 256 + col]);
        }
        uint4 pk;
        pk.x = (uint)us[0] | ((uint)us[1] << 16);
        pk.y = (uint)us[2] | ((uint)us[3] << 16);
        pk.z = (uint)us[4] | ((uint)us[5] << 16);
        pk.w = (uint)us[6] | ((uint)us[7] << 16);
        *((uint4*)(W1f + ((size_t)(ct * 4 + ks) * 64 + lane) * 8)) = pk;
    }
}

// ---------------- AT -> split-bf16 fragments (Ab + residual Ar) ----------------
// 1 block, 256 threads = 64 lanes x 4 ks. Lane&15 = score col, kmap for k.

__global__ void aprep_k(const float* __restrict__ AT, ushort* __restrict__ Abf,
                        ushort* __restrict__ Arf) {
    int t = threadIdx.x;
    int lane = t & 63, ks = t >> 6;
    int jcol = lane & 15, g = lane >> 4;
    ushort ub[8], ur[8];
    #pragma unroll
    for (int j = 0; j < 8; j++) {
        int k = ks * 32 + kmap(g, j);
        float v = AT[jcol * 128 + k];
        ub[j] = f2bf(v);
        ur[j] = f2bf(v - bf2f(ub[j]));
    }
    uint4 pb, pr;
    pb.x = (uint)ub[0] | ((uint)ub[1] << 16);
    pb.y = (uint)ub[2] | ((uint)ub[3] << 16);
    pb.z = (uint)ub[4] | ((uint)ub[5] << 16);
    pb.w = (uint)ub[6] | ((uint)ub[7] << 16);
    pr.x = (uint)ur[0] | ((uint)ur[1] << 16);
    pr.y = (uint)ur[2] | ((uint)ur[3] << 16);
    pr.z = (uint)ur[4] | ((uint)ur[5] << 16);
    pr.w = (uint)ur[6] | ((uint)ur[7] << 16);
    *((uint4*)(Abf + ((size_t)ks * 64 + lane) * 8)) = pb;
    *((uint4*)(Arf + ((size_t)ks * 64 + lane) * 8)) = pr;
}

// ---------------- fused layer-1: pack-in-reg + MFMA GEMM + split-MFMA scores ----
// 1 row-tile (16 rows) per wave, zero LDS, no __syncthreads.
// Swapped operands: mfma(Wfrag, xfrag) -> lane&15 = row, reg-dim = col
// (4 consecutive channels per lane -> coalesced uint2 / float4 stores).

__global__ __launch_bounds__(256) void fgemm1_k(
        const float* __restrict__ x, const ushort* __restrict__ W1f,
        const ushort* __restrict__ Abf, const ushort* __restrict__ Arf,
        ushort* __restrict__ h1u, float* __restrict__ s1s,
        float* __restrict__ s1d) {
    int lane = threadIdx.x & 63, wv = threadIdx.x >> 6;
    int rt = blockIdx.x * 4 + wv;
    if (rt >= N_RT) return;
    int r = lane & 15, g = lane >> 4;
    const float* xrow = x + ((size_t)rt * 16 + r) * 128;

    // ---- pack x fragments (bf16 main + bf16 residual) from coalesced loads ----
    v8s xb[4], xr[4];
    #pragma unroll
    for (int ks = 0; ks < 4; ks++) {
        float4 fa = *((const float4*)(xrow + ks * 32 + g * 4));
        float4 fb = *((const float4*)(xrow + ks * 32 + 16 + g * 4));
        ushort b0 = f2bf(fa.x), b1 = f2bf(fa.y), b2 = f2bf(fa.z), b3 = f2bf(fa.w);
        ushort b4 = f2bf(fb.x), b5 = f2bf(fb.y), b6 = f2bf(fb.z), b7 = f2bf(fb.w);
        uint4 p;
        p.x = (uint)b0 | ((uint)b1 << 16);
        p.y = (uint)b2 | ((uint)b3 << 16);
        p.z = (uint)b4 | ((uint)b5 << 16);
        p.w = (uint)b6 | ((uint)b7 << 16);
        xb[ks] = *((v8s*)&p);
        ushort r0 = f2bf(fa.x - bf2f(b0)), r1 = f2bf(fa.y - bf2f(b1));
        ushort r2 = f2bf(fa.z - bf2f(b2)), r3 = f2bf(fa.w - bf2f(b3));
        ushort r4 = f2bf(fb.x - bf2f(b4)), r5 = f2bf(fb.y - bf2f(b5));
        ushort r6 = f2bf(fb.z - bf2f(b6)), r7 = f2bf(fb.w - bf2f(b7));
        uint4 q;
        q.x = (uint)r0 | ((uint)r1 << 16);
        q.y = (uint)r2 | ((uint)r3 << 16);
        q.z = (uint)r4 | ((uint)r5 << 16);
        q.w = (uint)r6 | ((uint)r7 << 16);
        xr[ks] = *((v8s*)&q);
    }

    // ---- scores: split-bf16 MFMA (~f32 exact): xb*Ab + xb*Ar + xr*Ab ----
    f32x4 sacc = (f32x4){0.f, 0.f, 0.f, 0.f};
    const v8s* abp = (const v8s*)Abf;
    const v8s* arp = (const v8s*)Arf;
    #pragma unroll
    for (int ks = 0; ks < 4; ks++) {
        v8s ab = abp[ks * 64 + lane];
        v8s ar = arp[ks * 64 + lane];
        sacc = __builtin_amdgcn_mfma_f32_16x16x32_bf16(ab, xb[ks], sacc, 0, 0, 0);
        sacc = __builtin_amdgcn_mfma_f32_16x16x32_bf16(ar, xb[ks], sacc, 0, 0, 0);
        sacc = __builtin_amdgcn_mfma_f32_16x16x32_bf16(ab, xr[ks], sacc, 0, 0, 0);
    }
    {
        int row = rt * 16 + r;
        float4 sv;
        sv.x = sacc[0]; sv.y = sacc[1]; sv.z = sacc[2]; sv.w = sacc[3];
        if (g < 2) *((float4*)(s1s + (size_t)row * 8 + g * 4)) = sv;
        else       *((float4*)(s1d + (size_t)row * 8 + (g - 2) * 4)) = sv;
    }

    // ---- h1 = x @ W1 (bf16 MFMA, 16 col-tiles) ----
    f32x4 acc[16];
    #pragma unroll
    for (int ct = 0; ct < 16; ct++) acc[ct] = (f32x4){0.f, 0.f, 0.f, 0.f};
    const v8s* bp = (const v8s*)W1f;
    #pragma unroll
    for (int ks = 0; ks < 4; ks++) {
        #pragma unroll
        for (int ct = 0; ct < 16; ct++) {
            v8s wf = bp[(ct * 4 + ks) * 64 + lane];
            acc[ct] = __builtin_amdgcn_mfma_f32_16x16x32_bf16(wf, xb[ks], acc[ct], 0, 0, 0);
        }
    }

    // ---- coalesced bf16 store: lane holds 4 consecutive channels of row r ----
    ushort* hrow = h1u + ((size_t)rt * 16 + r) * 256;
    #pragma unroll
    for (int ct = 0; ct < 16; ct++) {
        uint lo = (uint)f2bf(acc[ct][0]) | ((uint)f2bf(acc[ct][1]) << 16);
        uint hi = (uint)f2bf(acc[ct][2]) | ((uint)f2bf(acc[ct][3]) << 16);
        *((uint2*)(hrow + ct * 16 + g * 4)) = make_uint2(lo, hi);
    }
}

// ---------------- Layer 1 softmax stats + fp16 alpha materialization ----------

__global__ __launch_bounds__(256) void stats1_k(
        const int* __restrict__ csr, const int* __restrict__ offs,
        const float* __restrict__ s1s, const float* __restrict__ s1d,
        __half* __restrict__ alpha) {
    int n = blockIdx.x * 4 + (threadIdx.x >> 6);
    if (n >= N_NODES) return;
    int lane = threadIdx.x & 63;
    int e8 = lane >> 3, h = lane & 7;
    int beg = offs[n], end = offs[n + 1];
    float sd = s1d[n * 8 + h];
    float m = -3.4e38f, d = 0.f;
    for (int i = beg + e8; i < end; i += 8) {
        int s = csr[i];
        float e = s1s[s * 8 + h] + sd;
        e = (e >= 0.f) ? e : 0.2f * e;
        float mn = fmaxf(m, e);
        d = d * __expf(m - mn) + __expf(e - mn);
        m = mn;
    }
    #pragma unroll
    for (int mask = 8; mask <= 32; mask <<= 1) {
        float om = __shfl_xor(m, mask);
        float od = __shfl_xor(d, mask);
        float nm = fmaxf(m, om);
        d = d * __expf(m - nm) + od * __expf(om - nm);
        m = nm;
    }
    float inv = 1.f / (d + 1e-16f);
    for (int i = beg + e8; i < end; i += 8) {
        int s = csr[i];
        float e = s1s[s * 8 + h] + sd;
        e = (e >= 0.f) ? e : 0.2f * e;
        alpha[(size_t)i * 8 + h] = __float2half(__expf(e - m) * inv);
    }
}

// ---------------- Layer 1 aggregation: pure bf16 gather ----------------
// 4 nodes / block, 64 lanes / node, 4 channels (uint2) / lane.

__global__ __launch_bounds__(256) void agg1_k(
        const int* __restrict__ csr, const int* __restrict__ offs,
        const ushort* __restrict__ h1u, const __half* __restrict__ alpha,
        const float* __restrict__ b1, float* __restrict__ hr) {
    int lane = threadIdx.x & 63;
    int n = blockIdx.x * 4 + (threadIdx.x >> 6);
    int h = lane >> 3;
    int beg = offs[n], end = offs[n + 1];
    const uint2* hv = (const uint2*)h1u;
    float acc0 = 0.f, acc1 = 0.f, acc2 = 0.f, acc3 = 0.f;
    int i = beg;
    for (; i + 1 < end; i += 2) {
        int s0 = csr[i], s1 = csr[i + 1];
        float a0 = __half2float(alpha[(size_t)i * 8 + h]);
        float a1 = __half2float(alpha[(size_t)(i + 1) * 8 + h]);
        uint2 v0 = hv[(size_t)s0 * 64 + lane];
        uint2 v1 = hv[(size_t)s1 * 64 + lane];
        acc0 = fmaf(a0, bflo(v0.x), acc0);
        acc1 = fmaf(a0, bfhi(v0.x), acc1);
        acc2 = fmaf(a0, bflo(v0.y), acc2);
        acc3 = fmaf(a0, bfhi(v0.y), acc3);
        acc0 = fmaf(a1, bflo(v1.x), acc0);
        acc1 = fmaf(a1, bfhi(v1.x), acc1);
        acc2 = fmaf(a1, bflo(v1.y), acc2);
        acc3 = fmaf(a1, bfhi(v1.y), acc3);
    }
    if (i < end) {
        int s0 = csr[i];
        float a0 = __half2float(alpha[(size_t)i * 8 + h]);
        uint2 v0 = hv[(size_t)s0 * 64 + lane];
        acc0 = fmaf(a0, bflo(v0.x), acc0);
        acc1 = fmaf(a0, bfhi(v0.x), acc1);
        acc2 = fmaf(a0, bflo(v0.y), acc2);
        acc3 = fmaf(a0, bfhi(v0.y), acc3);
    }
    int c0 = 4 * lane;
    float4 bv = *((const float4*)(b1 + c0));
    float4 o;
    o.x = fmaxf(acc0 + bv.x, 0.f);
    o.y = fmaxf(acc1 + bv.y, 0.f);
    o.z = fmaxf(acc2 + bv.z, 0.f);
    o.w = fmaxf(acc3 + bv.w, 0.f);
    ((float4*)hr)[(size_t)n * 64 + lane] = o;    // + b1, ReLU
}

// ---------------- Layer 2 GEMM (32-row tile, 4x1 per thread, LDS broadcast) --

__global__ __launch_bounds__(256) void gemm2_k(
        const float* __restrict__ hr, const float* __restrict__ W2,
        const float* __restrict__ a2s, const float* __restrict__ a2d,
        ushort* __restrict__ h2u, float* __restrict__ s2s,
        float* __restrict__ s2d) {
    __shared__ float hs[32][256];
    int tid = threadIdx.x;
    int row0 = blockIdx.x * 32;
    for (int i = tid; i < 32 * 64; i += 256) {
        int r = i >> 6, q = i & 63;
        int row = row0 + r; if (row >= N_NODES) row = N_NODES - 1;
        float4 v = ((const float4*)(hr + (size_t)row * 256))[q];
        *((float4*)&hs[r][q * 4]) = v;
    }
    __syncthreads();
    int c = tid & 31, g = tid >> 5;
    float acc[4] = {0.f, 0.f, 0.f, 0.f};
    for (int k = 0; k < 256; k += 4) {
        float w0 = W2[(size_t)(k + 0) * 32 + c];
        float w1 = W2[(size_t)(k + 1) * 32 + c];
        float w2 = W2[(size_t)(k + 2) * 32 + c];
        float w3 = W2[(size_t)(k + 3) * 32 + c];
        #pragma unroll
        for (int r = 0; r < 4; r++) {
            float4 xv = *((const float4*)&hs[g * 4 + r][k]);
            acc[r] = fmaf(xv.x, w0, acc[r]);
            acc[r] = fmaf(xv.y, w1, acc[r]);
            acc[r] = fmaf(xv.z, w2, acc[r]);
            acc[r] = fmaf(xv.w, w3, acc[r]);
        }
    }
    float av_s = a2s[c], av_d = a2d[c];
    #pragma unroll
    for (int r = 0; r < 4; r++) {
        int row = row0 + g * 4 + r;
        float ps = acc[r] * av_s, pd = acc[r] * av_d;
        #pragma unroll
        for (int mask = 16; mask >= 1; mask >>= 1) {
            ps += __shfl_xor(ps, mask);
            pd += __shfl_xor(pd, mask);
        }
        if (row < N_NODES) {
            h2u[(size_t)row * 32 + c] = f2bf(acc[r]);
            if (c == 0) { s2s[row] = ps; s2d[row] = pd; }
        }
    }
}

// ---------------- Layer 2: FUSED stats + aggregation ----------------
// 8 nodes / block, 32 lanes / node.

__global__ __launch_bounds__(256) void agg2_k(
        const int* __restrict__ csr, const int* __restrict__ offs,
        const ushort* __restrict__ h2u, const float* __restrict__ s2s,
        const float* __restrict__ s2d, const float* __restrict__ b2,
        float* __restrict__ out) {
    int l32 = threadIdx.x & 31;
    int n = blockIdx.x * 8 + (threadIdx.x >> 5);   // grid exact: 6250*8=50000
    int beg = offs[n], end = offs[n + 1];
    float sd = s2d[n];
    float m = -3.4e38f, dd = 0.f;
    for (int i = beg + l32; i < end; i += 32) {
        float e = s2s[csr[i]] + sd;
        e = (e >= 0.f) ? e : 0.2f * e;
        float mn = fmaxf(m, e);
        dd = dd * __expf(m - mn) + __expf(e - mn);
        m = mn;
    }
    #pragma unroll
    for (int mask = 1; mask <= 16; mask <<= 1) {
        float om = __shfl_xor(m, mask);
        float od = __shfl_xor(dd, mask);
        float nm = fmaxf(m, om);
        dd = dd * __expf(m - nm) + od * __expf(om - nm);
        m = nm;
    }
    float inv = 1.f / (dd + 1e-16f);
    float acc = 0.f;
    for (int c0 = beg; c0 < end; c0 += 32) {
        int cnt = min(32, end - c0);
        int s = 0; float a = 0.f;
        if (c0 + l32 < end) {
            s = csr[c0 + l32];
            float e = s2s[s] + sd;
            e = (e >= 0.f) ? e : 0.2f * e;
            a = __expf(e - m) * inv;
        }
        for (int e = 0; e < cnt; e++) {
            int se = __shfl(s, e, 32);
            float ae = __shfl(a, e, 32);
            acc = fmaf(ae, bf2f(h2u[(size_t)se * 32 + l32]), acc);
        }
    }
    out[(size_t)n * 32 + l32] = acc + b2[l32];
}

// ---------------- launch ----------------

extern "C" void kernel_launch(void* const* d_in, const int* in_sizes, int n_in,
                              void* d_out, int out_size, void* d_ws, size_t ws_size,
                              hipStream_t stream) {
    const float* x   = (const float*)d_in[0];
    const int*   ei  = (const int*)d_in[1];
    const float* W1  = (const float*)d_in[2];
    const float* a1s = (const float*)d_in[3];
    const float* a1d = (const float*)d_in[4];
    const float* b1  = (const float*)d_in[5];
    const float* W2  = (const float*)d_in[6];
    const float* a2s = (const float*)d_in[7];
    const float* a2d = (const float*)d_in[8];
    const float* b2  = (const float*)d_in[9];
    float* out = (float*)d_out;

    char* w = (char*)d_ws;
    float* hr     = (float*)w;  w += (size_t)N_NODES * 256 * 4;
    ushort* h1u   = (ushort*)w; w += (size_t)N_NODES * 256 * 2;
    ushort* W1f   = (ushort*)w; w += (size_t)16 * 4 * 64 * 8 * 2;
    ushort* Abf   = (ushort*)w; w += (size_t)4 * 64 * 8 * 2;
    ushort* Arf   = (ushort*)w; w += (size_t)4 * 64 * 8 * 2;
    float* AT     = (float*)w;  w += (size_t)16 * 128 * 4;
    ushort* h2u   = (ushort*)w; w += (size_t)N_NODES * 32 * 2;
    float* s1s    = (float*)w;  w += (size_t)N_NODES * 8 * 4;
    float* s1d    = (float*)w;  w += (size_t)N_NODES * 8 * 4;
    float* s2s    = (float*)w;  w += (size_t)N_NODES * 4;
    float* s2d    = (float*)w;  w += (size_t)N_NODES * 4;
    __half* alpha = (__half*)w; w += (size_t)E_TOT * 8 * 2;
    int* cnt    = (int*)w; w += (size_t)N_NODES * 4;
    int* offs   = (int*)w; w += (size_t)(N_NODES + 1) * 4;
    int* cursor = (int*)w; w += (size_t)(N_NODES + 4) * 4;
    int* bsum   = (int*)w; w += (size_t)NB_SCAN * 4;
    int* boffs  = (int*)w; w += (size_t)NB_SCAN * 4;
    int* csr    = (int*)w; w += (size_t)E_TOT * 4;

    hipMemsetAsync(cnt, 0, (size_t)N_NODES * 4, stream);
    hist_k<<<(E_TOT + 255) / 256, 256, 0, stream>>>(ei, cnt);
    scanA_k<<<NB_SCAN, 256, 0, stream>>>(cnt, offs, bsum);
    scanB_k<<<1, 256, 0, stream>>>(bsum, boffs);
    scanC_k<<<NB_SCAN, 256, 0, stream>>>(boffs, offs, cursor);
    scat_k<<<(E_TOT + 255) / 256, 256, 0, stream>>>(ei, cursor, csr);

    wprep_k<<<24, 256, 0, stream>>>(W1, a1s, a1d, AT, W1f);
    aprep_k<<<1, 256, 0, stream>>>(AT, Abf, Arf);
    fgemm1_k<<<(N_RT + 3) / 4, 256, 0, stream>>>(x, W1f, Abf, Arf, h1u, s1s, s1d);
    stats1_k<<<(N_NODES + 3) / 4, 256, 0, stream>>>(csr, offs, s1s, s1d, alpha);
    agg1_k<<<N_NODES / 4, 256, 0, stream>>>(csr, offs, h1u, alpha, b1, hr);
    gemm2_k<<<(N_NODES + 31) / 32, 256, 0, stream>>>(hr, W2, a2s, a2d, h2u, s2s, s2d);
    agg2_k<<<N_NODES / 8, 256, 0, stream>>>(csr, offs, h2u, s2s, s2d, b2, out);
}

// Round 10
// 280.229 us; speedup vs baseline: 1.1532x; 1.0862x over previous
//
#include <hip/hip_runtime.h>
#include <math.h>

#define N_NODES 50000
#define N_EDGES 800000
#define E_TOT (N_EDGES + N_NODES)
#define NB_SCAN ((N_NODES + 255) / 256)
#define N_RT 3125                 // N_NODES / 16 row-tiles (exact)

typedef unsigned int uint;
typedef unsigned short ushort;
typedef float f32x4 __attribute__((ext_vector_type(4)));
typedef short v8s __attribute__((ext_vector_type(8)));

__device__ __forceinline__ ushort f2bf(float f) {          // RNE f32->bf16
    uint u = __float_as_uint(f);
    return (ushort)((u + 0x7FFFu + ((u >> 16) & 1u)) >> 16);
}
__device__ __forceinline__ float bf2f(ushort u) {
    return __uint_as_float((uint)u << 16);
}
__device__ __forceinline__ float bflo(uint v) { return __uint_as_float(v << 16); }
__device__ __forceinline__ float bfhi(uint v) { return __uint_as_float(v & 0xFFFF0000u); }

// k-position inside a 32-k block for fragment lane-group g, elem j (consistent A/B)
__device__ __forceinline__ int kmap(int g, int j) {
    return ((j >> 2) << 4) + (g << 2) + (j & 3);
}

// ---------------- CSR build ----------------

__global__ void hist_k(const int* __restrict__ ei, int* __restrict__ cnt) {
    int e = blockIdx.x * blockDim.x + threadIdx.x;
    if (e < N_EDGES)      atomicAdd(&cnt[ei[N_EDGES + e]], 1);
    else if (e < E_TOT)   atomicAdd(&cnt[e - N_EDGES], 1);
}

__global__ __launch_bounds__(256) void scanA_k(const int* __restrict__ cnt,
                                               int* __restrict__ offs,
                                               int* __restrict__ bsum) {
    __shared__ int ws[4];
    int b = blockIdx.x, tid = threadIdx.x;
    int i = b * 256 + tid;
    int v = (i < N_NODES) ? cnt[i] : 0;
    int lane = tid & 63, w = tid >> 6;
    int x = v;
    #pragma unroll
    for (int d = 1; d < 64; d <<= 1) {
        int y = __shfl_up(x, d);
        if (lane >= d) x += y;
    }
    if (lane == 63) ws[w] = x;
    __syncthreads();
    if (tid == 0) {
        int s = 0;
        #pragma unroll
        for (int j = 0; j < 4; j++) { s += ws[j]; ws[j] = s; }
    }
    __syncthreads();
    int incl = x + (w ? ws[w - 1] : 0);
    if (i < N_NODES) offs[i + 1] = incl;
    if (tid == 255) bsum[b] = incl;
}

// scanC with inline block-prefix (replaces scanB): block b sums bsum[0..b)
__global__ __launch_bounds__(256) void scanC_k(const int* __restrict__ bsum,
                                               int* __restrict__ offs,
                                               int* __restrict__ cursor) {
    __shared__ int ws[4];
    __shared__ int bpref;
    int b = blockIdx.x, tid = threadIdx.x;
    int lane = tid & 63, w = tid >> 6;
    int v = (tid < b && tid < NB_SCAN) ? bsum[tid] : 0;
    #pragma unroll
    for (int mask = 1; mask <= 32; mask <<= 1) v += __shfl_xor(v, mask);
    if (lane == 0) ws[w] = v;
    __syncthreads();
    if (tid == 0) bpref = ws[0] + ws[1] + ws[2] + ws[3];
    __syncthreads();
    int i = b * 256 + tid;
    if (i == 0) { offs[0] = 0; cursor[0] = 0; }
    if (i < N_NODES) {
        int val = offs[i + 1] + bpref;
        offs[i + 1] = val;
        cursor[i + 1] = val;
    }
}

__global__ void scat_k(const int* __restrict__ ei, int* __restrict__ cursor,
                       int* __restrict__ csr) {
    int e = blockIdx.x * blockDim.x + threadIdx.x;
    int s, d;
    if (e < N_EDGES)      { s = ei[e]; d = ei[N_EDGES + e]; }
    else if (e < E_TOT)   { s = e - N_EDGES; d = s; }
    else return;
    int p = atomicAdd(&cursor[d], 1);
    csr[p] = s;
}

// ---------------- weight prep ----------------
// blocks 0..7:  AT = W1 @ [a1s|a1d]   (16 x 128 f32)
// blocks 8..23: W1f bf16 fragments [16ct][4ks][64lane][8j]
// blocks 24..27: W2 split-bf16 fragments [2ct][8ks][64lane][8j] (main + residual)

__global__ void wprep_k(const float* __restrict__ W1, const float* __restrict__ a1s,
                        const float* __restrict__ a1d, const float* __restrict__ W2,
                        float* __restrict__ AT, ushort* __restrict__ W1f,
                        ushort* __restrict__ W2b, ushort* __restrict__ W2r) {
    if (blockIdx.x < 8) {
        int idx = blockIdx.x * 256 + threadIdx.x;    // 0..2047
        int j = idx >> 7, k = idx & 127;
        int h = (j < 8) ? j : j - 8;
        const float* a = (j < 8) ? (a1s + h * 32) : (a1d + h * 32);
        const float* wrow = W1 + (size_t)k * 256 + h * 32;
        float s = 0.f;
        #pragma unroll 8
        for (int d = 0; d < 32; d++) s = fmaf(wrow[d], a[d], s);
        AT[j * 128 + k] = s;
    } else if (blockIdx.x < 24) {
        int idx = (blockIdx.x - 8) * 256 + threadIdx.x;   // 0..4095
        int lane = idx & 63, ks = (idx >> 6) & 3, ct = idx >> 8;
        int g = lane >> 4, col = ct * 16 + (lane & 15);
        ushort us[8];
        #pragma unroll
        for (int j = 0; j < 8; j++) {
            int k = ks * 32 + kmap(g, j);
            us[j] = f2bf(W1[(size_t)k * 256 + col]);
        }
        uint4 pk;
        pk.x = (uint)us[0] | ((uint)us[1] << 16);
        pk.y = (uint)us[2] | ((uint)us[3] << 16);
        pk.z = (uint)us[4] | ((uint)us[5] << 16);
        pk.w = (uint)us[6] | ((uint)us[7] << 16);
        *((uint4*)(W1f + ((size_t)(ct * 4 + ks) * 64 + lane) * 8)) = pk;
    } else {
        int idx = (blockIdx.x - 24) * 256 + threadIdx.x;  // 0..1023
        int lane = idx & 63, ks = (idx >> 6) & 7, ct = idx >> 9;
        int g = lane >> 4, col = ct * 16 + (lane & 15);
        ushort ub[8], ur[8];
        #pragma unroll
        for (int j = 0; j < 8; j++) {
            int k = ks * 32 + kmap(g, j);
            float v = W2[(size_t)k * 32 + col];
            ub[j] = f2bf(v);
            ur[j] = f2bf(v - bf2f(ub[j]));
        }
        uint4 pb, pr;
        pb.x = (uint)ub[0] | ((uint)ub[1] << 16);
        pb.y = (uint)ub[2] | ((uint)ub[3] << 16);
        pb.z = (uint)ub[4] | ((uint)ub[5] << 16);
        pb.w = (uint)ub[6] | ((uint)ub[7] << 16);
        pr.x = (uint)ur[0] | ((uint)ur[1] << 16);
        pr.y = (uint)ur[2] | ((uint)ur[3] << 16);
        pr.z = (uint)ur[4] | ((uint)ur[5] << 16);
        pr.w = (uint)ur[6] | ((uint)ur[7] << 16);
        *((uint4*)(W2b + ((size_t)(ct * 8 + ks) * 64 + lane) * 8)) = pb;
        *((uint4*)(W2r + ((size_t)(ct * 8 + ks) * 64 + lane) * 8)) = pr;
    }
}

// ---------------- AT -> split-bf16 fragments (Ab + residual Ar) ----------------

__global__ void aprep_k(const float* __restrict__ AT, ushort* __restrict__ Abf,
                        ushort* __restrict__ Arf) {
    int t = threadIdx.x;
    int lane = t & 63, ks = t >> 6;
    int jcol = lane & 15, g = lane >> 4;
    ushort ub[8], ur[8];
    #pragma unroll
    for (int j = 0; j < 8; j++) {
        int k = ks * 32 + kmap(g, j);
        float v = AT[jcol * 128 + k];
        ub[j] = f2bf(v);
        ur[j] = f2bf(v - bf2f(ub[j]));
    }
    uint4 pb, pr;
    pb.x = (uint)ub[0] | ((uint)ub[1] << 16);
    pb.y = (uint)ub[2] | ((uint)ub[3] << 16);
    pb.z = (uint)ub[4] | ((uint)ub[5] << 16);
    pb.w = (uint)ub[6] | ((uint)ub[7] << 16);
    pr.x = (uint)ur[0] | ((uint)ur[1] << 16);
    pr.y = (uint)ur[2] | ((uint)ur[3] << 16);
    pr.z = (uint)ur[4] | ((uint)ur[5] << 16);
    pr.w = (uint)ur[6] | ((uint)ur[7] << 16);
    *((uint4*)(Abf + ((size_t)ks * 64 + lane) * 8)) = pb;
    *((uint4*)(Arf + ((size_t)ks * 64 + lane) * 8)) = pr;
}

// ---------------- fused layer-1: pack-in-reg + MFMA GEMM + split-MFMA scores ----

__global__ __launch_bounds__(256) void fgemm1_k(
        const float* __restrict__ x, const ushort* __restrict__ W1f,
        const ushort* __restrict__ Abf, const ushort* __restrict__ Arf,
        ushort* __restrict__ h1u, float* __restrict__ s1s,
        float* __restrict__ s1d) {
    int lane = threadIdx.x & 63, wv = threadIdx.x >> 6;
    int rt = blockIdx.x * 4 + wv;
    if (rt >= N_RT) return;
    int r = lane & 15, g = lane >> 4;
    const float* xrow = x + ((size_t)rt * 16 + r) * 128;

    v8s xb[4], xr[4];
    #pragma unroll
    for (int ks = 0; ks < 4; ks++) {
        float4 fa = *((const float4*)(xrow + ks * 32 + g * 4));
        float4 fb = *((const float4*)(xrow + ks * 32 + 16 + g * 4));
        ushort b0 = f2bf(fa.x), b1 = f2bf(fa.y), b2 = f2bf(fa.z), b3 = f2bf(fa.w);
        ushort b4 = f2bf(fb.x), b5 = f2bf(fb.y), b6 = f2bf(fb.z), b7 = f2bf(fb.w);
        uint4 p;
        p.x = (uint)b0 | ((uint)b1 << 16);
        p.y = (uint)b2 | ((uint)b3 << 16);
        p.z = (uint)b4 | ((uint)b5 << 16);
        p.w = (uint)b6 | ((uint)b7 << 16);
        xb[ks] = *((v8s*)&p);
        ushort r0 = f2bf(fa.x - bf2f(b0)), r1 = f2bf(fa.y - bf2f(b1));
        ushort r2 = f2bf(fa.z - bf2f(b2)), r3 = f2bf(fa.w - bf2f(b3));
        ushort r4 = f2bf(fb.x - bf2f(b4)), r5 = f2bf(fb.y - bf2f(b5));
        ushort r6 = f2bf(fb.z - bf2f(b6)), r7 = f2bf(fb.w - bf2f(b7));
        uint4 q;
        q.x = (uint)r0 | ((uint)r1 << 16);
        q.y = (uint)r2 | ((uint)r3 << 16);
        q.z = (uint)r4 | ((uint)r5 << 16);
        q.w = (uint)r6 | ((uint)r7 << 16);
        xr[ks] = *((v8s*)&q);
    }

    f32x4 sacc = (f32x4){0.f, 0.f, 0.f, 0.f};
    const v8s* abp = (const v8s*)Abf;
    const v8s* arp = (const v8s*)Arf;
    #pragma unroll
    for (int ks = 0; ks < 4; ks++) {
        v8s ab = abp[ks * 64 + lane];
        v8s ar = arp[ks * 64 + lane];
        sacc = __builtin_amdgcn_mfma_f32_16x16x32_bf16(ab, xb[ks], sacc, 0, 0, 0);
        sacc = __builtin_amdgcn_mfma_f32_16x16x32_bf16(ar, xb[ks], sacc, 0, 0, 0);
        sacc = __builtin_amdgcn_mfma_f32_16x16x32_bf16(ab, xr[ks], sacc, 0, 0, 0);
    }
    {
        int row = rt * 16 + r;
        float4 sv;
        sv.x = sacc[0]; sv.y = sacc[1]; sv.z = sacc[2]; sv.w = sacc[3];
        if (g < 2) *((float4*)(s1s + (size_t)row * 8 + g * 4)) = sv;
        else       *((float4*)(s1d + (size_t)row * 8 + (g - 2) * 4)) = sv;
    }

    f32x4 acc[16];
    #pragma unroll
    for (int ct = 0; ct < 16; ct++) acc[ct] = (f32x4){0.f, 0.f, 0.f, 0.f};
    const v8s* bp = (const v8s*)W1f;
    #pragma unroll
    for (int ks = 0; ks < 4; ks++) {
        #pragma unroll
        for (int ct = 0; ct < 16; ct++) {
            v8s wf = bp[(ct * 4 + ks) * 64 + lane];
            acc[ct] = __builtin_amdgcn_mfma_f32_16x16x32_bf16(wf, xb[ks], acc[ct], 0, 0, 0);
        }
    }

    ushort* hrow = h1u + ((size_t)rt * 16 + r) * 256;
    #pragma unroll
    for (int ct = 0; ct < 16; ct++) {
        uint lo = (uint)f2bf(acc[ct][0]) | ((uint)f2bf(acc[ct][1]) << 16);
        uint hi = (uint)f2bf(acc[ct][2]) | ((uint)f2bf(acc[ct][3]) << 16);
        *((uint2*)(hrow + ct * 16 + g * 4)) = make_uint2(lo, hi);
    }
}

// ---------------- Layer 1: FUSED softmax stats + alpha + gather ----------------
// 1 node / wave, 4 waves / block.
// Phase A (stats): lane = (e8 = lane>>3, h8 = lane&7), online (m,d), butterfly
// over e8 bits -> per-head (m, inv). Phase B: per 8-edge chunk compute alpha
// once per (edge, head) in the phase-A layout, shfl-broadcast into gather FMAs.
// Output row hr in bf16 (uint2 per lane).

__global__ __launch_bounds__(256) void agg1_k(
        const int* __restrict__ csr, const int* __restrict__ offs,
        const ushort* __restrict__ h1u, const float* __restrict__ s1s,
        const float* __restrict__ s1d, const float* __restrict__ b1,
        ushort* __restrict__ hrb) {
    int lane = threadIdx.x & 63;
    int n = blockIdx.x * 4 + (threadIdx.x >> 6);   // grid exact: 12500*4
    int e8 = lane >> 3, h8 = lane & 7;
    int H = lane >> 3;                              // phase-B head of ch 4*lane..
    int beg = offs[n], end = offs[n + 1];

    // ---- phase A: per-head online softmax stats ----
    float sdA = s1d[n * 8 + h8];
    float m = -3.4e38f, d = 0.f;
    for (int i = beg + e8; i < end; i += 8) {
        float e = s1s[csr[i] * 8 + h8] + sdA;
        e = (e >= 0.f) ? e : 0.2f * e;
        float mn = fmaxf(m, e);
        d = d * __expf(m - mn) + __expf(e - mn);
        m = mn;
    }
    #pragma unroll
    for (int mask = 8; mask <= 32; mask <<= 1) {
        float om = __shfl_xor(m, mask);
        float od = __shfl_xor(d, mask);
        float nm = fmaxf(m, om);
        d = d * __expf(m - nm) + od * __expf(om - nm);
        m = nm;
    }
    float inv = 1.f / (d + 1e-16f);

    // ---- phase B: chunked alpha + gather ----
    const uint2* hv = (const uint2*)h1u;
    float acc0 = 0.f, acc1 = 0.f, acc2 = 0.f, acc3 = 0.f;
    for (int c0 = beg; c0 < end; c0 += 8) {
        int i = c0 + e8;
        int sA = 0; float aA = 0.f;
        if (i < end) {
            sA = csr[i];
            float e = s1s[sA * 8 + h8] + sdA;
            e = (e >= 0.f) ? e : 0.2f * e;
            aA = __expf(e - m) * inv;
        }
        int nsub = min(8, end - c0);                // wave-uniform bound
        for (int e = 0; e < nsub; e++) {
            int src = e * 8 + H;
            int se = __shfl(sA, src);
            float ae = __shfl(aA, src);
            uint2 v = hv[(size_t)se * 64 + lane];
            acc0 = fmaf(ae, bflo(v.x), acc0);
            acc1 = fmaf(ae, bfhi(v.x), acc1);
            acc2 = fmaf(ae, bflo(v.y), acc2);
            acc3 = fmaf(ae, bfhi(v.y), acc3);
        }
    }
    int c0ch = 4 * lane;
    float4 bv = *((const float4*)(b1 + c0ch));
    float o0 = fmaxf(acc0 + bv.x, 0.f);
    float o1 = fmaxf(acc1 + bv.y, 0.f);
    float o2 = fmaxf(acc2 + bv.z, 0.f);
    float o3 = fmaxf(acc3 + bv.w, 0.f);
    uint lo = (uint)f2bf(o0) | ((uint)f2bf(o1) << 16);
    uint hi = (uint)f2bf(o2) | ((uint)f2bf(o3) << 16);
    ((uint2*)hrb)[(size_t)n * 64 + lane] = make_uint2(lo, hi);
}

// ---------------- Layer 2 GEMM: MFMA on bf16 hr, split-bf16 W2 ----------------
// 1 row-tile (16 rows) / wave; h2 + scores fused.

__global__ __launch_bounds__(256) void gemm2m_k(
        const ushort* __restrict__ hrb, const ushort* __restrict__ W2b,
        const ushort* __restrict__ W2r, const float* __restrict__ a2s,
        const float* __restrict__ a2d, ushort* __restrict__ h2u,
        float* __restrict__ s2s, float* __restrict__ s2d) {
    int lane = threadIdx.x & 63, wv = threadIdx.x >> 6;
    int rt = blockIdx.x * 4 + wv;
    if (rt >= N_RT) return;
    int r = lane & 15, g = lane >> 4;
    int row = rt * 16 + r;
    const ushort* arow = hrb + (size_t)row * 256;

    v8s af[8];
    #pragma unroll
    for (int ks = 0; ks < 8; ks++) {
        uint2 u0 = *((const uint2*)(arow + ks * 32 + g * 4));
        uint2 u1 = *((const uint2*)(arow + ks * 32 + 16 + g * 4));
        uint4 p; p.x = u0.x; p.y = u0.y; p.z = u1.x; p.w = u1.y;
        af[ks] = *((v8s*)&p);
    }

    f32x4 acc[2];
    acc[0] = (f32x4){0.f, 0.f, 0.f, 0.f};
    acc[1] = (f32x4){0.f, 0.f, 0.f, 0.f};
    const v8s* wbp = (const v8s*)W2b;
    const v8s* wrp = (const v8s*)W2r;
    #pragma unroll
    for (int ks = 0; ks < 8; ks++) {
        #pragma unroll
        for (int ct = 0; ct < 2; ct++) {
            v8s wb = wbp[(ct * 8 + ks) * 64 + lane];
            v8s wr = wrp[(ct * 8 + ks) * 64 + lane];
            acc[ct] = __builtin_amdgcn_mfma_f32_16x16x32_bf16(wb, af[ks], acc[ct], 0, 0, 0);
            acc[ct] = __builtin_amdgcn_mfma_f32_16x16x32_bf16(wr, af[ks], acc[ct], 0, 0, 0);
        }
    }

    // scores: per-lane partial over its 8 cols, reduce over g (masks 16,32)
    float ps = 0.f, pd = 0.f;
    #pragma unroll
    for (int ct = 0; ct < 2; ct++) {
        #pragma unroll
        for (int q = 0; q < 4; q++) {
            int c = ct * 16 + g * 4 + q;
            ps = fmaf(acc[ct][q], a2s[c], ps);
            pd = fmaf(acc[ct][q], a2d[c], pd);
        }
    }
    ps += __shfl_xor(ps, 16); ps += __shfl_xor(ps, 32);
    pd += __shfl_xor(pd, 16); pd += __shfl_xor(pd, 32);
    if (g == 0) { s2s[row] = ps; s2d[row] = pd; }

    #pragma unroll
    for (int ct = 0; ct < 2; ct++) {
        uint lo = (uint)f2bf(acc[ct][0]) | ((uint)f2bf(acc[ct][1]) << 16);
        uint hi = (uint)f2bf(acc[ct][2]) | ((uint)f2bf(acc[ct][3]) << 16);
        *((uint2*)(h2u + (size_t)row * 32 + ct * 16 + g * 4)) = make_uint2(lo, hi);
    }
}

// ---------------- Layer 2: FUSED stats + parallel gather ----------------
// 1 node / wave. Stats: 64-edge parallel + butterfly. Gather: 64-edge
// superchunks of lane-parallel alpha; 4 edges x 16 lanes concurrent FMA.

__global__ __launch_bounds__(256) void agg2_k(
        const int* __restrict__ csr, const int* __restrict__ offs,
        const ushort* __restrict__ h2u, const float* __restrict__ s2s,
        const float* __restrict__ s2d, const float* __restrict__ b2,
        float* __restrict__ out) {
    int lane = threadIdx.x & 63;
    int n = blockIdx.x * 4 + (threadIdx.x >> 6);   // grid exact: 12500*4
    int beg = offs[n], end = offs[n + 1];
    float sd = s2d[n];

    float m = -3.4e38f, dd = 0.f;
    for (int i = beg + lane; i < end; i += 64) {
        float e = s2s[csr[i]] + sd;
        e = (e >= 0.f) ? e : 0.2f * e;
        float mn = fmaxf(m, e);
        dd = dd * __expf(m - mn) + __expf(e - mn);
        m = mn;
    }
    #pragma unroll
    for (int mask = 1; mask <= 32; mask <<= 1) {
        float om = __shfl_xor(m, mask);
        float od = __shfl_xor(dd, mask);
        float nm = fmaxf(m, om);
        dd = dd * __expf(m - nm) + od * __expf(om - nm);
        m = nm;
    }
    float inv = 1.f / (dd + 1e-16f);

    int e4 = lane >> 4, cp = lane & 15;            // edge-slot, channel-pair
    float acc0 = 0.f, acc1 = 0.f;
    for (int c0 = beg; c0 < end; c0 += 64) {
        int i = c0 + lane;
        int sL = 0; float aL = 0.f;
        if (i < end) {
            sL = csr[i];
            float e = s2s[sL] + sd;
            e = (e >= 0.f) ? e : 0.2f * e;
            aL = __expf(e - m) * inv;
        }
        int nsub = min(64, end - c0);               // wave-uniform
        for (int el = 0; el < nsub; el += 4) {
            int local = el + e4;
            int se = __shfl(sL, local);
            float ae = __shfl(aL, local);
            uint v = *((const uint*)(h2u + (size_t)se * 32 + cp * 2));
            acc0 = fmaf(ae, bflo(v), acc0);
            acc1 = fmaf(ae, bfhi(v), acc1);
        }
    }
    acc0 += __shfl_xor(acc0, 16); acc0 += __shfl_xor(acc0, 32);
    acc1 += __shfl_xor(acc1, 16); acc1 += __shfl_xor(acc1, 32);
    if (lane < 16) {
        float2 bv = ((const float2*)b2)[cp];
        float2 o; o.x = acc0 + bv.x; o.y = acc1 + bv.y;
        ((float2*)(out + (size_t)n * 32))[cp] = o;
    }
}

// ---------------- launch ----------------

extern "C" void kernel_launch(void* const* d_in, const int* in_sizes, int n_in,
                              void* d_out, int out_size, void* d_ws, size_t ws_size,
                              hipStream_t stream) {
    const float* x   = (const float*)d_in[0];
    const int*   ei  = (const int*)d_in[1];
    const float* W1  = (const float*)d_in[2];
    const float* a1s = (const float*)d_in[3];
    const float* a1d = (const float*)d_in[4];
    const float* b1  = (const float*)d_in[5];
    const float* W2  = (const float*)d_in[6];
    const float* a2s = (const float*)d_in[7];
    const float* a2d = (const float*)d_in[8];
    const float* b2  = (const float*)d_in[9];
    float* out = (float*)d_out;

    char* w = (char*)d_ws;
    ushort* h1u   = (ushort*)w; w += (size_t)N_NODES * 256 * 2;
    ushort* hrb   = (ushort*)w; w += (size_t)N_NODES * 256 * 2;
    ushort* W1f   = (ushort*)w; w += (size_t)16 * 4 * 64 * 8 * 2;
    ushort* Abf   = (ushort*)w; w += (size_t)4 * 64 * 8 * 2;
    ushort* Arf   = (ushort*)w; w += (size_t)4 * 64 * 8 * 2;
    ushort* W2b   = (ushort*)w; w += (size_t)2 * 8 * 64 * 8 * 2;
    ushort* W2r   = (ushort*)w; w += (size_t)2 * 8 * 64 * 8 * 2;
    float* AT     = (float*)w;  w += (size_t)16 * 128 * 4;
    ushort* h2u   = (ushort*)w; w += (size_t)N_NODES * 32 * 2;
    float* s1s    = (float*)w;  w += (size_t)N_NODES * 8 * 4;
    float* s1d    = (float*)w;  w += (size_t)N_NODES * 8 * 4;
    float* s2s    = (float*)w;  w += (size_t)N_NODES * 4;
    float* s2d    = (float*)w;  w += (size_t)N_NODES * 4;
    int* cnt    = (int*)w; w += (size_t)N_NODES * 4;
    int* offs   = (int*)w; w += (size_t)(N_NODES + 1) * 4;
    int* cursor = (int*)w; w += (size_t)(N_NODES + 4) * 4;
    int* bsum   = (int*)w; w += (size_t)NB_SCAN * 4;
    int* csr    = (int*)w; w += (size_t)E_TOT * 4;

    hipMemsetAsync(cnt, 0, (size_t)N_NODES * 4, stream);
    hist_k<<<(E_TOT + 255) / 256, 256, 0, stream>>>(ei, cnt);
    scanA_k<<<NB_SCAN, 256, 0, stream>>>(cnt, offs, bsum);
    scanC_k<<<NB_SCAN, 256, 0, stream>>>(bsum, offs, cursor);
    scat_k<<<(E_TOT + 255) / 256, 256, 0, stream>>>(ei, cursor, csr);

    wprep_k<<<28, 256, 0, stream>>>(W1, a1s, a1d, W2, AT, W1f, W2b, W2r);
    aprep_k<<<1, 256, 0, stream>>>(AT, Abf, Arf);
    fgemm1_k<<<(N_RT + 3) / 4, 256, 0, stream>>>(x, W1f, Abf, Arf, h1u, s1s, s1d);
    agg1_k<<<N_NODES / 4, 256, 0, stream>>>(csr, offs, h1u, s1s, s1d, b1, hrb);
    gemm2m_k<<<(N_RT + 3) / 4, 256, 0, stream>>>(hrb, W2b, W2r, a2s, a2d, h2u, s2s, s2d);
    agg2_k<<<N_NODES / 4, 256, 0, stream>>>(csr, offs, h2u, s2s, s2d, b2, out);
}

// Round 11
// 279.774 us; speedup vs baseline: 1.1550x; 1.0016x over previous
//
#include <hip/hip_runtime.h>
#include <hip/hip_fp16.h>
#include <math.h>

#define N_NODES 50000
#define N_EDGES 800000
#define E_TOT (N_EDGES + N_NODES)
#define NB_SCAN ((N_NODES + 255) / 256)
#define N_RT 3125                 // N_NODES / 16 row-tiles (exact)

typedef unsigned int uint;
typedef unsigned short ushort;
typedef float f32x4 __attribute__((ext_vector_type(4)));
typedef short v8s __attribute__((ext_vector_type(8)));

__device__ __forceinline__ ushort f2bf(float f) {          // RNE f32->bf16
    uint u = __float_as_uint(f);
    return (ushort)((u + 0x7FFFu + ((u >> 16) & 1u)) >> 16);
}
__device__ __forceinline__ float bf2f(ushort u) {
    return __uint_as_float((uint)u << 16);
}
__device__ __forceinline__ float bflo(uint v) { return __uint_as_float(v << 16); }
__device__ __forceinline__ float bfhi(uint v) { return __uint_as_float(v & 0xFFFF0000u); }

// k-position inside a 32-k block for fragment lane-group g, elem j (consistent A/B)
__device__ __forceinline__ int kmap(int g, int j) {
    return ((j >> 2) << 4) + (g << 2) + (j & 3);
}

// ---------------- CSR build ----------------

__global__ void hist_k(const int* __restrict__ ei, int* __restrict__ cnt) {
    int e = blockIdx.x * blockDim.x + threadIdx.x;
    if (e < N_EDGES)      atomicAdd(&cnt[ei[N_EDGES + e]], 1);
    else if (e < E_TOT)   atomicAdd(&cnt[e - N_EDGES], 1);
}

__global__ __launch_bounds__(256) void scanA_k(const int* __restrict__ cnt,
                                               int* __restrict__ offs,
                                               int* __restrict__ bsum) {
    __shared__ int ws[4];
    int b = blockIdx.x, tid = threadIdx.x;
    int i = b * 256 + tid;
    int v = (i < N_NODES) ? cnt[i] : 0;
    int lane = tid & 63, w = tid >> 6;
    int x = v;
    #pragma unroll
    for (int d = 1; d < 64; d <<= 1) {
        int y = __shfl_up(x, d);
        if (lane >= d) x += y;
    }
    if (lane == 63) ws[w] = x;
    __syncthreads();
    if (tid == 0) {
        int s = 0;
        #pragma unroll
        for (int j = 0; j < 4; j++) { s += ws[j]; ws[j] = s; }
    }
    __syncthreads();
    int incl = x + (w ? ws[w - 1] : 0);
    if (i < N_NODES) offs[i + 1] = incl;
    if (tid == 255) bsum[b] = incl;
}

// scanC with inline block-prefix: block b sums bsum[0..b)
__global__ __launch_bounds__(256) void scanC_k(const int* __restrict__ bsum,
                                               int* __restrict__ offs,
                                               int* __restrict__ cursor) {
    __shared__ int ws[4];
    __shared__ int bpref;
    int b = blockIdx.x, tid = threadIdx.x;
    int lane = tid & 63, w = tid >> 6;
    int v = (tid < b && tid < NB_SCAN) ? bsum[tid] : 0;
    #pragma unroll
    for (int mask = 1; mask <= 32; mask <<= 1) v += __shfl_xor(v, mask);
    if (lane == 0) ws[w] = v;
    __syncthreads();
    if (tid == 0) bpref = ws[0] + ws[1] + ws[2] + ws[3];
    __syncthreads();
    int i = b * 256 + tid;
    if (i == 0) { offs[0] = 0; cursor[0] = 0; }
    if (i < N_NODES) {
        int val = offs[i + 1] + bpref;
        offs[i + 1] = val;
        cursor[i + 1] = val;
    }
}

__global__ void scat_k(const int* __restrict__ ei, int* __restrict__ cursor,
                       int* __restrict__ csr) {
    int e = blockIdx.x * blockDim.x + threadIdx.x;
    int s, d;
    if (e < N_EDGES)      { s = ei[e]; d = ei[N_EDGES + e]; }
    else if (e < E_TOT)   { s = e - N_EDGES; d = s; }
    else return;
    int p = atomicAdd(&cursor[d], 1);
    csr[p] = s;
}

// ---------------- weight prep ----------------
// blocks 0..7:  AT = W1 @ [a1s|a1d]   (16 x 128 f32)
// blocks 8..23: W1f bf16 fragments [16ct][4ks][64lane][8j]
// blocks 24..27: W2 split-bf16 fragments [2ct][8ks][64lane][8j] (main + residual)

__global__ void wprep_k(const float* __restrict__ W1, const float* __restrict__ a1s,
                        const float* __restrict__ a1d, const float* __restrict__ W2,
                        float* __restrict__ AT, ushort* __restrict__ W1f,
                        ushort* __restrict__ W2b, ushort* __restrict__ W2r) {
    if (blockIdx.x < 8) {
        int idx = blockIdx.x * 256 + threadIdx.x;    // 0..2047
        int j = idx >> 7, k = idx & 127;
        int h = (j < 8) ? j : j - 8;
        const float* a = (j < 8) ? (a1s + h * 32) : (a1d + h * 32);
        const float* wrow = W1 + (size_t)k * 256 + h * 32;
        float s = 0.f;
        #pragma unroll 8
        for (int d = 0; d < 32; d++) s = fmaf(wrow[d], a[d], s);
        AT[j * 128 + k] = s;
    } else if (blockIdx.x < 24) {
        int idx = (blockIdx.x - 8) * 256 + threadIdx.x;   // 0..4095
        int lane = idx & 63, ks = (idx >> 6) & 3, ct = idx >> 8;
        int g = lane >> 4, col = ct * 16 + (lane & 15);
        ushort us[8];
        #pragma unroll
        for (int j = 0; j < 8; j++) {
            int k = ks * 32 + kmap(g, j);
            us[j] = f2bf(W1[(size_t)k * 256 + col]);
        }
        uint4 pk;
        pk.x = (uint)us[0] | ((uint)us[1] << 16);
        pk.y = (uint)us[2] | ((uint)us[3] << 16);
        pk.z = (uint)us[4] | ((uint)us[5] << 16);
        pk.w = (uint)us[6] | ((uint)us[7] << 16);
        *((uint4*)(W1f + ((size_t)(ct * 4 + ks) * 64 + lane) * 8)) = pk;
    } else {
        int idx = (blockIdx.x - 24) * 256 + threadIdx.x;  // 0..1023
        int lane = idx & 63, ks = (idx >> 6) & 7, ct = idx >> 9;
        int g = lane >> 4, col = ct * 16 + (lane & 15);
        ushort ub[8], ur[8];
        #pragma unroll
        for (int j = 0; j < 8; j++) {
            int k = ks * 32 + kmap(g, j);
            float v = W2[(size_t)k * 32 + col];
            ub[j] = f2bf(v);
            ur[j] = f2bf(v - bf2f(ub[j]));
        }
        uint4 pb, pr;
        pb.x = (uint)ub[0] | ((uint)ub[1] << 16);
        pb.y = (uint)ub[2] | ((uint)ub[3] << 16);
        pb.z = (uint)ub[4] | ((uint)ub[5] << 16);
        pb.w = (uint)ub[6] | ((uint)ub[7] << 16);
        pr.x = (uint)ur[0] | ((uint)ur[1] << 16);
        pr.y = (uint)ur[2] | ((uint)ur[3] << 16);
        pr.z = (uint)ur[4] | ((uint)ur[5] << 16);
        pr.w = (uint)ur[6] | ((uint)ur[7] << 16);
        *((uint4*)(W2b + ((size_t)(ct * 8 + ks) * 64 + lane) * 8)) = pb;
        *((uint4*)(W2r + ((size_t)(ct * 8 + ks) * 64 + lane) * 8)) = pr;
    }
}

// ---------------- AT -> split-bf16 fragments (Ab + residual Ar) ----------------

__global__ void aprep_k(const float* __restrict__ AT, ushort* __restrict__ Abf,
                        ushort* __restrict__ Arf) {
    int t = threadIdx.x;
    int lane = t & 63, ks = t >> 6;
    int jcol = lane & 15, g = lane >> 4;
    ushort ub[8], ur[8];
    #pragma unroll
    for (int j = 0; j < 8; j++) {
        int k = ks * 32 + kmap(g, j);
        float v = AT[jcol * 128 + k];
        ub[j] = f2bf(v);
        ur[j] = f2bf(v - bf2f(ub[j]));
    }
    uint4 pb, pr;
    pb.x = (uint)ub[0] | ((uint)ub[1] << 16);
    pb.y = (uint)ub[2] | ((uint)ub[3] << 16);
    pb.z = (uint)ub[4] | ((uint)ub[5] << 16);
    pb.w = (uint)ub[6] | ((uint)ub[7] << 16);
    pr.x = (uint)ur[0] | ((uint)ur[1] << 16);
    pr.y = (uint)ur[2] | ((uint)ur[3] << 16);
    pr.z = (uint)ur[4] | ((uint)ur[5] << 16);
    pr.w = (uint)ur[6] | ((uint)ur[7] << 16);
    *((uint4*)(Abf + ((size_t)ks * 64 + lane) * 8)) = pb;
    *((uint4*)(Arf + ((size_t)ks * 64 + lane) * 8)) = pr;
}

// ---------------- fused layer-1: pack-in-reg + MFMA GEMM + split-MFMA scores ----

__global__ __launch_bounds__(256) void fgemm1_k(
        const float* __restrict__ x, const ushort* __restrict__ W1f,
        const ushort* __restrict__ Abf, const ushort* __restrict__ Arf,
        ushort* __restrict__ h1u, float* __restrict__ s1s,
        float* __restrict__ s1d) {
    int lane = threadIdx.x & 63, wv = threadIdx.x >> 6;
    int rt = blockIdx.x * 4 + wv;
    if (rt >= N_RT) return;
    int r = lane & 15, g = lane >> 4;
    const float* xrow = x + ((size_t)rt * 16 + r) * 128;

    v8s xb[4], xr[4];
    #pragma unroll
    for (int ks = 0; ks < 4; ks++) {
        float4 fa = *((const float4*)(xrow + ks * 32 + g * 4));
        float4 fb = *((const float4*)(xrow + ks * 32 + 16 + g * 4));
        ushort b0 = f2bf(fa.x), b1 = f2bf(fa.y), b2 = f2bf(fa.z), b3 = f2bf(fa.w);
        ushort b4 = f2bf(fb.x), b5 = f2bf(fb.y), b6 = f2bf(fb.z), b7 = f2bf(fb.w);
        uint4 p;
        p.x = (uint)b0 | ((uint)b1 << 16);
        p.y = (uint)b2 | ((uint)b3 << 16);
        p.z = (uint)b4 | ((uint)b5 << 16);
        p.w = (uint)b6 | ((uint)b7 << 16);
        xb[ks] = *((v8s*)&p);
        ushort r0 = f2bf(fa.x - bf2f(b0)), r1 = f2bf(fa.y - bf2f(b1));
        ushort r2 = f2bf(fa.z - bf2f(b2)), r3 = f2bf(fa.w - bf2f(b3));
        ushort r4 = f2bf(fb.x - bf2f(b4)), r5 = f2bf(fb.y - bf2f(b5));
        ushort r6 = f2bf(fb.z - bf2f(b6)), r7 = f2bf(fb.w - bf2f(b7));
        uint4 q;
        q.x = (uint)r0 | ((uint)r1 << 16);
        q.y = (uint)r2 | ((uint)r3 << 16);
        q.z = (uint)r4 | ((uint)r5 << 16);
        q.w = (uint)r6 | ((uint)r7 << 16);
        xr[ks] = *((v8s*)&q);
    }

    f32x4 sacc = (f32x4){0.f, 0.f, 0.f, 0.f};
    const v8s* abp = (const v8s*)Abf;
    const v8s* arp = (const v8s*)Arf;
    #pragma unroll
    for (int ks = 0; ks < 4; ks++) {
        v8s ab = abp[ks * 64 + lane];
        v8s ar = arp[ks * 64 + lane];
        sacc = __builtin_amdgcn_mfma_f32_16x16x32_bf16(ab, xb[ks], sacc, 0, 0, 0);
        sacc = __builtin_amdgcn_mfma_f32_16x16x32_bf16(ar, xb[ks], sacc, 0, 0, 0);
        sacc = __builtin_amdgcn_mfma_f32_16x16x32_bf16(ab, xr[ks], sacc, 0, 0, 0);
    }
    {
        int row = rt * 16 + r;
        float4 sv;
        sv.x = sacc[0]; sv.y = sacc[1]; sv.z = sacc[2]; sv.w = sacc[3];
        if (g < 2) *((float4*)(s1s + (size_t)row * 8 + g * 4)) = sv;
        else       *((float4*)(s1d + (size_t)row * 8 + (g - 2) * 4)) = sv;
    }

    f32x4 acc[16];
    #pragma unroll
    for (int ct = 0; ct < 16; ct++) acc[ct] = (f32x4){0.f, 0.f, 0.f, 0.f};
    const v8s* bp = (const v8s*)W1f;
    #pragma unroll
    for (int ks = 0; ks < 4; ks++) {
        #pragma unroll
        for (int ct = 0; ct < 16; ct++) {
            v8s wf = bp[(ct * 4 + ks) * 64 + lane];
            acc[ct] = __builtin_amdgcn_mfma_f32_16x16x32_bf16(wf, xb[ks], acc[ct], 0, 0, 0);
        }
    }

    ushort* hrow = h1u + ((size_t)rt * 16 + r) * 256;
    #pragma unroll
    for (int ct = 0; ct < 16; ct++) {
        uint lo = (uint)f2bf(acc[ct][0]) | ((uint)f2bf(acc[ct][1]) << 16);
        uint hi = (uint)f2bf(acc[ct][2]) | ((uint)f2bf(acc[ct][3]) << 16);
        *((uint2*)(hrow + ct * 16 + g * 4)) = make_uint2(lo, hi);
    }
}

// ---------------- Layer 1 softmax stats + fp16 alpha materialization ----------

__global__ __launch_bounds__(256) void stats1_k(
        const int* __restrict__ csr, const int* __restrict__ offs,
        const float* __restrict__ s1s, const float* __restrict__ s1d,
        __half* __restrict__ alpha) {
    int n = blockIdx.x * 4 + (threadIdx.x >> 6);   // grid exact
    int lane = threadIdx.x & 63;
    int e8 = lane >> 3, h = lane & 7;
    int beg = offs[n], end = offs[n + 1];
    float sd = s1d[n * 8 + h];
    float m = -3.4e38f, d = 0.f;
    for (int i = beg + e8; i < end; i += 8) {
        int s = csr[i];
        float e = s1s[s * 8 + h] + sd;
        e = (e >= 0.f) ? e : 0.2f * e;
        float mn = fmaxf(m, e);
        d = d * __expf(m - mn) + __expf(e - mn);
        m = mn;
    }
    #pragma unroll
    for (int mask = 8; mask <= 32; mask <<= 1) {
        float om = __shfl_xor(m, mask);
        float od = __shfl_xor(d, mask);
        float nm = fmaxf(m, om);
        d = d * __expf(m - nm) + od * __expf(om - nm);
        m = nm;
    }
    float inv = 1.f / (d + 1e-16f);
    for (int i = beg + e8; i < end; i += 8) {
        int s = csr[i];
        float e = s1s[s * 8 + h] + sd;
        e = (e >= 0.f) ? e : 0.2f * e;
        alpha[(size_t)i * 8 + h] = __float2half(__expf(e - m) * inv);
    }
}

// ---------------- Layer 1 aggregation: pure bf16 gather -> bf16 out ----------
// 4 nodes / block, 64 lanes / node, 4 channels (uint2) / lane.

__global__ __launch_bounds__(256) void agg1_k(
        const int* __restrict__ csr, const int* __restrict__ offs,
        const ushort* __restrict__ h1u, const __half* __restrict__ alpha,
        const float* __restrict__ b1, ushort* __restrict__ hrb) {
    int lane = threadIdx.x & 63;
    int n = blockIdx.x * 4 + (threadIdx.x >> 6);   // grid exact
    int h = lane >> 3;                    // head of channels 4*lane..4*lane+3
    int beg = offs[n], end = offs[n + 1];
    const uint2* hv = (const uint2*)h1u;
    float acc0 = 0.f, acc1 = 0.f, acc2 = 0.f, acc3 = 0.f;
    int i = beg;
    for (; i + 1 < end; i += 2) {
        int s0 = csr[i], s1 = csr[i + 1];
        float a0 = __half2float(alpha[(size_t)i * 8 + h]);
        float a1 = __half2float(alpha[(size_t)(i + 1) * 8 + h]);
        uint2 v0 = hv[(size_t)s0 * 64 + lane];
        uint2 v1 = hv[(size_t)s1 * 64 + lane];
        acc0 = fmaf(a0, bflo(v0.x), acc0);
        acc1 = fmaf(a0, bfhi(v0.x), acc1);
        acc2 = fmaf(a0, bflo(v0.y), acc2);
        acc3 = fmaf(a0, bfhi(v0.y), acc3);
        acc0 = fmaf(a1, bflo(v1.x), acc0);
        acc1 = fmaf(a1, bfhi(v1.x), acc1);
        acc2 = fmaf(a1, bflo(v1.y), acc2);
        acc3 = fmaf(a1, bfhi(v1.y), acc3);
    }
    if (i < end) {
        int s0 = csr[i];
        float a0 = __half2float(alpha[(size_t)i * 8 + h]);
        uint2 v0 = hv[(size_t)s0 * 64 + lane];
        acc0 = fmaf(a0, bflo(v0.x), acc0);
        acc1 = fmaf(a0, bfhi(v0.x), acc1);
        acc2 = fmaf(a0, bflo(v0.y), acc2);
        acc3 = fmaf(a0, bfhi(v0.y), acc3);
    }
    int c0 = 4 * lane;
    float4 bv = *((const float4*)(b1 + c0));
    float o0 = fmaxf(acc0 + bv.x, 0.f);
    float o1 = fmaxf(acc1 + bv.y, 0.f);
    float o2 = fmaxf(acc2 + bv.z, 0.f);
    float o3 = fmaxf(acc3 + bv.w, 0.f);
    uint lo = (uint)f2bf(o0) | ((uint)f2bf(o1) << 16);
    uint hi = (uint)f2bf(o2) | ((uint)f2bf(o3) << 16);
    ((uint2*)hrb)[(size_t)n * 64 + lane] = make_uint2(lo, hi);   // + b1, ReLU
}

// ---------------- Layer 2 GEMM: MFMA on bf16 hr, split-bf16 W2 ----------------
// 1 row-tile (16 rows) / wave; h2 + scores fused.

__global__ __launch_bounds__(256) void gemm2m_k(
        const ushort* __restrict__ hrb, const ushort* __restrict__ W2b,
        const ushort* __restrict__ W2r, const float* __restrict__ a2s,
        const float* __restrict__ a2d, ushort* __restrict__ h2u,
        float* __restrict__ s2s, float* __restrict__ s2d) {
    int lane = threadIdx.x & 63, wv = threadIdx.x >> 6;
    int rt = blockIdx.x * 4 + wv;
    if (rt >= N_RT) return;
    int r = lane & 15, g = lane >> 4;
    int row = rt * 16 + r;
    const ushort* arow = hrb + (size_t)row * 256;

    v8s af[8];
    #pragma unroll
    for (int ks = 0; ks < 8; ks++) {
        uint2 u0 = *((const uint2*)(arow + ks * 32 + g * 4));
        uint2 u1 = *((const uint2*)(arow + ks * 32 + 16 + g * 4));
        uint4 p; p.x = u0.x; p.y = u0.y; p.z = u1.x; p.w = u1.y;
        af[ks] = *((v8s*)&p);
    }

    f32x4 acc[2];
    acc[0] = (f32x4){0.f, 0.f, 0.f, 0.f};
    acc[1] = (f32x4){0.f, 0.f, 0.f, 0.f};
    const v8s* wbp = (const v8s*)W2b;
    const v8s* wrp = (const v8s*)W2r;
    #pragma unroll
    for (int ks = 0; ks < 8; ks++) {
        #pragma unroll
        for (int ct = 0; ct < 2; ct++) {
            v8s wb = wbp[(ct * 8 + ks) * 64 + lane];
            v8s wr = wrp[(ct * 8 + ks) * 64 + lane];
            acc[ct] = __builtin_amdgcn_mfma_f32_16x16x32_bf16(wb, af[ks], acc[ct], 0, 0, 0);
            acc[ct] = __builtin_amdgcn_mfma_f32_16x16x32_bf16(wr, af[ks], acc[ct], 0, 0, 0);
        }
    }

    float ps = 0.f, pd = 0.f;
    #pragma unroll
    for (int ct = 0; ct < 2; ct++) {
        #pragma unroll
        for (int q = 0; q < 4; q++) {
            int c = ct * 16 + g * 4 + q;
            ps = fmaf(acc[ct][q], a2s[c], ps);
            pd = fmaf(acc[ct][q], a2d[c], pd);
        }
    }
    ps += __shfl_xor(ps, 16); ps += __shfl_xor(ps, 32);
    pd += __shfl_xor(pd, 16); pd += __shfl_xor(pd, 32);
    if (g == 0) { s2s[row] = ps; s2d[row] = pd; }

    #pragma unroll
    for (int ct = 0; ct < 2; ct++) {
        uint lo = (uint)f2bf(acc[ct][0]) | ((uint)f2bf(acc[ct][1]) << 16);
        uint hi = (uint)f2bf(acc[ct][2]) | ((uint)f2bf(acc[ct][3]) << 16);
        *((uint2*)(h2u + (size_t)row * 32 + ct * 16 + g * 4)) = make_uint2(lo, hi);
    }
}

// ---------------- Layer 2: FUSED stats + parallel gather ----------------
// 1 node / wave. Stats: 64-edge parallel + butterfly. Gather: 64-edge
// superchunks of lane-parallel alpha; 4 edges x 16 lanes concurrent FMA.

__global__ __launch_bounds__(256) void agg2_k(
        const int* __restrict__ csr, const int* __restrict__ offs,
        const ushort* __restrict__ h2u, const float* __restrict__ s2s,
        const float* __restrict__ s2d, const float* __restrict__ b2,
        float* __restrict__ out) {
    int lane = threadIdx.x & 63;
    int n = blockIdx.x * 4 + (threadIdx.x >> 6);   // grid exact: 12500*4
    int beg = offs[n], end = offs[n + 1];
    float sd = s2d[n];

    float m = -3.4e38f, dd = 0.f;
    for (int i = beg + lane; i < end; i += 64) {
        float e = s2s[csr[i]] + sd;
        e = (e >= 0.f) ? e : 0.2f * e;
        float mn = fmaxf(m, e);
        dd = dd * __expf(m - mn) + __expf(e - mn);
        m = mn;
    }
    #pragma unroll
    for (int mask = 1; mask <= 32; mask <<= 1) {
        float om = __shfl_xor(m, mask);
        float od = __shfl_xor(dd, mask);
        float nm = fmaxf(m, om);
        dd = dd * __expf(m - nm) + od * __expf(om - nm);
        m = nm;
    }
    float inv = 1.f / (dd + 1e-16f);

    int e4 = lane >> 4, cp = lane & 15;            // edge-slot, channel-pair
    float acc0 = 0.f, acc1 = 0.f;
    for (int c0 = beg; c0 < end; c0 += 64) {
        int i = c0 + lane;
        int sL = 0; float aL = 0.f;
        if (i < end) {
            sL = csr[i];
            float e = s2s[sL] + sd;
            e = (e >= 0.f) ? e : 0.2f * e;
            aL = __expf(e - m) * inv;
        }
        int nsub = min(64, end - c0);               // wave-uniform
        for (int el = 0; el < nsub; el += 4) {
            int local = el + e4;
            int se = __shfl(sL, local);
            float ae = __shfl(aL, local);
            uint v = *((const uint*)(h2u + (size_t)se * 32 + cp * 2));
            acc0 = fmaf(ae, bflo(v), acc0);
            acc1 = fmaf(ae, bfhi(v), acc1);
        }
    }
    acc0 += __shfl_xor(acc0, 16); acc0 += __shfl_xor(acc0, 32);
    acc1 += __shfl_xor(acc1, 16); acc1 += __shfl_xor(acc1, 32);
    if (lane < 16) {
        float2 bv = ((const float2*)b2)[cp];
        float2 o; o.x = acc0 + bv.x; o.y = acc1 + bv.y;
        ((float2*)(out + (size_t)n * 32))[cp] = o;
    }
}

// ---------------- launch ----------------

extern "C" void kernel_launch(void* const* d_in, const int* in_sizes, int n_in,
                              void* d_out, int out_size, void* d_ws, size_t ws_size,
                              hipStream_t stream) {
    const float* x   = (const float*)d_in[0];
    const int*   ei  = (const int*)d_in[1];
    const float* W1  = (const float*)d_in[2];
    const float* a1s = (const float*)d_in[3];
    const float* a1d = (const float*)d_in[4];
    const float* b1  = (const float*)d_in[5];
    const float* W2  = (const float*)d_in[6];
    const float* a2s = (const float*)d_in[7];
    const float* a2d = (const float*)d_in[8];
    const float* b2  = (const float*)d_in[9];
    float* out = (float*)d_out;

    char* w = (char*)d_ws;
    ushort* h1u   = (ushort*)w; w += (size_t)N_NODES * 256 * 2;
    ushort* hrb   = (ushort*)w; w += (size_t)N_NODES * 256 * 2;
    ushort* W1f   = (ushort*)w; w += (size_t)16 * 4 * 64 * 8 * 2;
    ushort* Abf   = (ushort*)w; w += (size_t)4 * 64 * 8 * 2;
    ushort* Arf   = (ushort*)w; w += (size_t)4 * 64 * 8 * 2;
    ushort* W2b   = (ushort*)w; w += (size_t)2 * 8 * 64 * 8 * 2;
    ushort* W2r   = (ushort*)w; w += (size_t)2 * 8 * 64 * 8 * 2;
    float* AT     = (float*)w;  w += (size_t)16 * 128 * 4;
    ushort* h2u   = (ushort*)w; w += (size_t)N_NODES * 32 * 2;
    float* s1s    = (float*)w;  w += (size_t)N_NODES * 8 * 4;
    float* s1d    = (float*)w;  w += (size_t)N_NODES * 8 * 4;
    float* s2s    = (float*)w;  w += (size_t)N_NODES * 4;
    float* s2d    = (float*)w;  w += (size_t)N_NODES * 4;
    __half* alpha = (__half*)w; w += (size_t)E_TOT * 8 * 2;
    int* cnt    = (int*)w; w += (size_t)N_NODES * 4;
    int* offs   = (int*)w; w += (size_t)(N_NODES + 1) * 4;
    int* cursor = (int*)w; w += (size_t)(N_NODES + 4) * 4;
    int* bsum   = (int*)w; w += (size_t)NB_SCAN * 4;
    int* csr    = (int*)w; w += (size_t)E_TOT * 4;

    hipMemsetAsync(cnt, 0, (size_t)N_NODES * 4, stream);
    hist_k<<<(E_TOT + 255) / 256, 256, 0, stream>>>(ei, cnt);
    scanA_k<<<NB_SCAN, 256, 0, stream>>>(cnt, offs, bsum);
    scanC_k<<<NB_SCAN, 256, 0, stream>>>(bsum, offs, cursor);
    scat_k<<<(E_TOT + 255) / 256, 256, 0, stream>>>(ei, cursor, csr);

    wprep_k<<<28, 256, 0, stream>>>(W1, a1s, a1d, W2, AT, W1f, W2b, W2r);
    aprep_k<<<1, 256, 0, stream>>>(AT, Abf, Arf);
    fgemm1_k<<<(N_RT + 3) / 4, 256, 0, stream>>>(x, W1f, Abf, Arf, h1u, s1s, s1d);
    stats1_k<<<N_NODES / 4, 256, 0, stream>>>(csr, offs, s1s, s1d, alpha);
    agg1_k<<<N_NODES / 4, 256, 0, stream>>>(csr, offs, h1u, alpha, b1, hrb);
    gemm2m_k<<<(N_RT + 3) / 4, 256, 0, stream>>>(hrb, W2b, W2r, a2s, a2d, h2u, s2s, s2d);
    agg2_k<<<N_NODES / 4, 256, 0, stream>>>(csr, offs, h2u, s2s, s2d, b2, out);
}

// Round 12
// 279.759 us; speedup vs baseline: 1.1551x; 1.0001x over previous
//
#include <hip/hip_runtime.h>
#include <hip/hip_fp16.h>
#include <math.h>

#define N_NODES 50000
#define N_EDGES 800000
#define E_TOT (N_EDGES + N_NODES)
#define NB_SCAN ((N_NODES + 255) / 256)
#define N_RT 3125                 // N_NODES / 16 row-tiles (exact)

typedef unsigned int uint;
typedef unsigned short ushort;
typedef float f32x4 __attribute__((ext_vector_type(4)));
typedef short v8s __attribute__((ext_vector_type(8)));

__device__ __forceinline__ ushort f2bf(float f) {          // RNE f32->bf16
    uint u = __float_as_uint(f);
    return (ushort)((u + 0x7FFFu + ((u >> 16) & 1u)) >> 16);
}
__device__ __forceinline__ float bf2f(ushort u) {
    return __uint_as_float((uint)u << 16);
}
__device__ __forceinline__ float bflo(uint v) { return __uint_as_float(v << 16); }
__device__ __forceinline__ float bfhi(uint v) { return __uint_as_float(v & 0xFFFF0000u); }

// k-position inside a 32-k block for fragment lane-group g, elem j (consistent A/B)
__device__ __forceinline__ int kmap(int g, int j) {
    return ((j >> 2) << 4) + (g << 2) + (j & 3);
}

// ---------------- CSR build ----------------

__global__ void hist_k(const int* __restrict__ ei, int* __restrict__ cnt) {
    int e = blockIdx.x * blockDim.x + threadIdx.x;
    if (e < N_EDGES)      atomicAdd(&cnt[ei[N_EDGES + e]], 1);
    else if (e < E_TOT)   atomicAdd(&cnt[e - N_EDGES], 1);
}

__global__ __launch_bounds__(256) void scanA_k(const int* __restrict__ cnt,
                                               int* __restrict__ offs,
                                               int* __restrict__ bsum) {
    __shared__ int ws[4];
    int b = blockIdx.x, tid = threadIdx.x;
    int i = b * 256 + tid;
    int v = (i < N_NODES) ? cnt[i] : 0;
    int lane = tid & 63, w = tid >> 6;
    int x = v;
    #pragma unroll
    for (int d = 1; d < 64; d <<= 1) {
        int y = __shfl_up(x, d);
        if (lane >= d) x += y;
    }
    if (lane == 63) ws[w] = x;
    __syncthreads();
    if (tid == 0) {
        int s = 0;
        #pragma unroll
        for (int j = 0; j < 4; j++) { s += ws[j]; ws[j] = s; }
    }
    __syncthreads();
    int incl = x + (w ? ws[w - 1] : 0);
    if (i < N_NODES) offs[i + 1] = incl;
    if (tid == 255) bsum[b] = incl;
}

// scanC with inline block-prefix: block b sums bsum[0..b)
__global__ __launch_bounds__(256) void scanC_k(const int* __restrict__ bsum,
                                               int* __restrict__ offs,
                                               int* __restrict__ cursor) {
    __shared__ int ws[4];
    __shared__ int bpref;
    int b = blockIdx.x, tid = threadIdx.x;
    int lane = tid & 63, w = tid >> 6;
    int v = (tid < b && tid < NB_SCAN) ? bsum[tid] : 0;
    #pragma unroll
    for (int mask = 1; mask <= 32; mask <<= 1) v += __shfl_xor(v, mask);
    if (lane == 0) ws[w] = v;
    __syncthreads();
    if (tid == 0) bpref = ws[0] + ws[1] + ws[2] + ws[3];
    __syncthreads();
    int i = b * 256 + tid;
    if (i == 0) { offs[0] = 0; cursor[0] = 0; }
    if (i < N_NODES) {
        int val = offs[i + 1] + bpref;
        offs[i + 1] = val;
        cursor[i + 1] = val;
    }
}

__global__ void scat_k(const int* __restrict__ ei, int* __restrict__ cursor,
                       int* __restrict__ csr) {
    int e = blockIdx.x * blockDim.x + threadIdx.x;
    int s, d;
    if (e < N_EDGES)      { s = ei[e]; d = ei[N_EDGES + e]; }
    else if (e < E_TOT)   { s = e - N_EDGES; d = s; }
    else return;
    int p = atomicAdd(&cursor[d], 1);
    csr[p] = s;
}

// ---------------- weight prep (single dispatch, 21 blocks) ----------------
// blocks 0..15: W1f bf16 fragments [16ct][4ks][64lane][8j]
// blocks 16..19: W2 split-bf16 fragments [2ct][8ks][64lane][8j]
// block 20: A = W1 @ [a1s|a1d] split-bf16 fragments (computed directly)
// all blocks: grid-stride zero of cnt (replaces memset dispatch)

__global__ void wprep_k(const float* __restrict__ W1, const float* __restrict__ a1s,
                        const float* __restrict__ a1d, const float* __restrict__ W2,
                        ushort* __restrict__ W1f, ushort* __restrict__ W2b,
                        ushort* __restrict__ W2r, ushort* __restrict__ Abf,
                        ushort* __restrict__ Arf, int* __restrict__ cnt) {
    for (int i = blockIdx.x * 256 + threadIdx.x; i < N_NODES; i += 21 * 256)
        cnt[i] = 0;

    if (blockIdx.x < 16) {
        int idx = blockIdx.x * 256 + threadIdx.x;         // 0..4095
        int lane = idx & 63, ks = (idx >> 6) & 3, ct = idx >> 8;
        int g = lane >> 4, col = ct * 16 + (lane & 15);
        ushort us[8];
        #pragma unroll
        for (int j = 0; j < 8; j++) {
            int k = ks * 32 + kmap(g, j);
            us[j] = f2bf(W1[(size_t)k * 256 + col]);
        }
        uint4 pk;
        pk.x = (uint)us[0] | ((uint)us[1] << 16);
        pk.y = (uint)us[2] | ((uint)us[3] << 16);
        pk.z = (uint)us[4] | ((uint)us[5] << 16);
        pk.w = (uint)us[6] | ((uint)us[7] << 16);
        *((uint4*)(W1f + ((size_t)(ct * 4 + ks) * 64 + lane) * 8)) = pk;
    } else if (blockIdx.x < 20) {
        int idx = (blockIdx.x - 16) * 256 + threadIdx.x;  // 0..1023
        int lane = idx & 63, ks = (idx >> 6) & 7, ct = idx >> 9;
        int g = lane >> 4, col = ct * 16 + (lane & 15);
        ushort ub[8], ur[8];
        #pragma unroll
        for (int j = 0; j < 8; j++) {
            int k = ks * 32 + kmap(g, j);
            float v = W2[(size_t)k * 32 + col];
            ub[j] = f2bf(v);
            ur[j] = f2bf(v - bf2f(ub[j]));
        }
        uint4 pb, pr;
        pb.x = (uint)ub[0] | ((uint)ub[1] << 16);
        pb.y = (uint)ub[2] | ((uint)ub[3] << 16);
        pb.z = (uint)ub[4] | ((uint)ub[5] << 16);
        pb.w = (uint)ub[6] | ((uint)ub[7] << 16);
        pr.x = (uint)ur[0] | ((uint)ur[1] << 16);
        pr.y = (uint)ur[2] | ((uint)ur[3] << 16);
        pr.z = (uint)ur[4] | ((uint)ur[5] << 16);
        pr.w = (uint)ur[6] | ((uint)ur[7] << 16);
        *((uint4*)(W2b + ((size_t)(ct * 8 + ks) * 64 + lane) * 8)) = pb;
        *((uint4*)(W2r + ((size_t)(ct * 8 + ks) * 64 + lane) * 8)) = pr;
    } else {
        // A-fragments computed directly: AT[j][k] = dot(W1[k][h*32:+32], a_j)
        int t = threadIdx.x;
        int lane = t & 63, ks = t >> 6;
        int jcol = lane & 15, g = lane >> 4;
        int hh = (jcol < 8) ? jcol : jcol - 8;
        const float* a = (jcol < 8) ? (a1s + hh * 32) : (a1d + hh * 32);
        ushort ub[8], ur[8];
        #pragma unroll
        for (int j = 0; j < 8; j++) {
            int k = ks * 32 + kmap(g, j);
            const float* wrow = W1 + (size_t)k * 256 + hh * 32;
            float v = 0.f;
            #pragma unroll 8
            for (int d = 0; d < 32; d++) v = fmaf(wrow[d], a[d], v);
            ub[j] = f2bf(v);
            ur[j] = f2bf(v - bf2f(ub[j]));
        }
        uint4 pb, pr;
        pb.x = (uint)ub[0] | ((uint)ub[1] << 16);
        pb.y = (uint)ub[2] | ((uint)ub[3] << 16);
        pb.z = (uint)ub[4] | ((uint)ub[5] << 16);
        pb.w = (uint)ub[6] | ((uint)ub[7] << 16);
        pr.x = (uint)ur[0] | ((uint)ur[1] << 16);
        pr.y = (uint)ur[2] | ((uint)ur[3] << 16);
        pr.z = (uint)ur[4] | ((uint)ur[5] << 16);
        pr.w = (uint)ur[6] | ((uint)ur[7] << 16);
        *((uint4*)(Abf + ((size_t)ks * 64 + lane) * 8)) = pb;
        *((uint4*)(Arf + ((size_t)ks * 64 + lane) * 8)) = pr;
    }
}

// ---------------- fused layer-1: pack-in-reg + MFMA GEMM + split-MFMA scores ----

__global__ __launch_bounds__(256) void fgemm1_k(
        const float* __restrict__ x, const ushort* __restrict__ W1f,
        const ushort* __restrict__ Abf, const ushort* __restrict__ Arf,
        ushort* __restrict__ h1u, float* __restrict__ s1s,
        float* __restrict__ s1d) {
    int lane = threadIdx.x & 63, wv = threadIdx.x >> 6;
    int rt = blockIdx.x * 4 + wv;
    if (rt >= N_RT) return;
    int r = lane & 15, g = lane >> 4;
    const float* xrow = x + ((size_t)rt * 16 + r) * 128;

    v8s xb[4], xr[4];
    #pragma unroll
    for (int ks = 0; ks < 4; ks++) {
        float4 fa = *((const float4*)(xrow + ks * 32 + g * 4));
        float4 fb = *((const float4*)(xrow + ks * 32 + 16 + g * 4));
        ushort b0 = f2bf(fa.x), b1 = f2bf(fa.y), b2 = f2bf(fa.z), b3 = f2bf(fa.w);
        ushort b4 = f2bf(fb.x), b5 = f2bf(fb.y), b6 = f2bf(fb.z), b7 = f2bf(fb.w);
        uint4 p;
        p.x = (uint)b0 | ((uint)b1 << 16);
        p.y = (uint)b2 | ((uint)b3 << 16);
        p.z = (uint)b4 | ((uint)b5 << 16);
        p.w = (uint)b6 | ((uint)b7 << 16);
        xb[ks] = *((v8s*)&p);
        ushort r0 = f2bf(fa.x - bf2f(b0)), r1 = f2bf(fa.y - bf2f(b1));
        ushort r2 = f2bf(fa.z - bf2f(b2)), r3 = f2bf(fa.w - bf2f(b3));
        ushort r4 = f2bf(fb.x - bf2f(b4)), r5 = f2bf(fb.y - bf2f(b5));
        ushort r6 = f2bf(fb.z - bf2f(b6)), r7 = f2bf(fb.w - bf2f(b7));
        uint4 q;
        q.x = (uint)r0 | ((uint)r1 << 16);
        q.y = (uint)r2 | ((uint)r3 << 16);
        q.z = (uint)r4 | ((uint)r5 << 16);
        q.w = (uint)r6 | ((uint)r7 << 16);
        xr[ks] = *((v8s*)&q);
    }

    f32x4 sacc = (f32x4){0.f, 0.f, 0.f, 0.f};
    const v8s* abp = (const v8s*)Abf;
    const v8s* arp = (const v8s*)Arf;
    #pragma unroll
    for (int ks = 0; ks < 4; ks++) {
        v8s ab = abp[ks * 64 + lane];
        v8s ar = arp[ks * 64 + lane];
        sacc = __builtin_amdgcn_mfma_f32_16x16x32_bf16(ab, xb[ks], sacc, 0, 0, 0);
        sacc = __builtin_amdgcn_mfma_f32_16x16x32_bf16(ar, xb[ks], sacc, 0, 0, 0);
        sacc = __builtin_amdgcn_mfma_f32_16x16x32_bf16(ab, xr[ks], sacc, 0, 0, 0);
    }
    {
        int row = rt * 16 + r;
        float4 sv;
        sv.x = sacc[0]; sv.y = sacc[1]; sv.z = sacc[2]; sv.w = sacc[3];
        if (g < 2) *((float4*)(s1s + (size_t)row * 8 + g * 4)) = sv;
        else       *((float4*)(s1d + (size_t)row * 8 + (g - 2) * 4)) = sv;
    }

    f32x4 acc[16];
    #pragma unroll
    for (int ct = 0; ct < 16; ct++) acc[ct] = (f32x4){0.f, 0.f, 0.f, 0.f};
    const v8s* bp = (const v8s*)W1f;
    #pragma unroll
    for (int ks = 0; ks < 4; ks++) {
        #pragma unroll
        for (int ct = 0; ct < 16; ct++) {
            v8s wf = bp[(ct * 4 + ks) * 64 + lane];
            acc[ct] = __builtin_amdgcn_mfma_f32_16x16x32_bf16(wf, xb[ks], acc[ct], 0, 0, 0);
        }
    }

    ushort* hrow = h1u + ((size_t)rt * 16 + r) * 256;
    #pragma unroll
    for (int ct = 0; ct < 16; ct++) {
        uint lo = (uint)f2bf(acc[ct][0]) | ((uint)f2bf(acc[ct][1]) << 16);
        uint hi = (uint)f2bf(acc[ct][2]) | ((uint)f2bf(acc[ct][3]) << 16);
        *((uint2*)(hrow + ct * 16 + g * 4)) = make_uint2(lo, hi);
    }
}

// ---------------- Layer 1 softmax stats + fp16 alpha materialization ----------

__global__ __launch_bounds__(256) void stats1_k(
        const int* __restrict__ csr, const int* __restrict__ offs,
        const float* __restrict__ s1s, const float* __restrict__ s1d,
        __half* __restrict__ alpha) {
    int n = blockIdx.x * 4 + (threadIdx.x >> 6);   // grid exact
    int lane = threadIdx.x & 63;
    int e8 = lane >> 3, h = lane & 7;
    int beg = offs[n], end = offs[n + 1];
    float sd = s1d[n * 8 + h];
    float m = -3.4e38f, d = 0.f;
    for (int i = beg + e8; i < end; i += 8) {
        int s = csr[i];
        float e = s1s[s * 8 + h] + sd;
        e = (e >= 0.f) ? e : 0.2f * e;
        float mn = fmaxf(m, e);
        d = d * __expf(m - mn) + __expf(e - mn);
        m = mn;
    }
    #pragma unroll
    for (int mask = 8; mask <= 32; mask <<= 1) {
        float om = __shfl_xor(m, mask);
        float od = __shfl_xor(d, mask);
        float nm = fmaxf(m, om);
        d = d * __expf(m - nm) + od * __expf(om - nm);
        m = nm;
    }
    float inv = 1.f / (d + 1e-16f);
    for (int i = beg + e8; i < end; i += 8) {
        int s = csr[i];
        float e = s1s[s * 8 + h] + sd;
        e = (e >= 0.f) ? e : 0.2f * e;
        alpha[(size_t)i * 8 + h] = __float2half(__expf(e - m) * inv);
    }
}

// ---------------- Layer 1 aggregation: pure bf16 gather (4x unroll) ----------
// 4 nodes / block, 64 lanes / node, 4 channels (uint2) / lane.

__global__ __launch_bounds__(256) void agg1_k(
        const int* __restrict__ csr, const int* __restrict__ offs,
        const ushort* __restrict__ h1u, const __half* __restrict__ alpha,
        const float* __restrict__ b1, ushort* __restrict__ hrb) {
    int lane = threadIdx.x & 63;
    int n = blockIdx.x * 4 + (threadIdx.x >> 6);   // grid exact
    int h = lane >> 3;
    int beg = offs[n], end = offs[n + 1];
    const uint2* hv = (const uint2*)h1u;
    float acc0 = 0.f, acc1 = 0.f, acc2 = 0.f, acc3 = 0.f;
    int i = beg;
    for (; i + 3 < end; i += 4) {
        int s0 = csr[i], s1 = csr[i + 1], s2 = csr[i + 2], s3 = csr[i + 3];
        float a0 = __half2float(alpha[(size_t)i * 8 + h]);
        float a1 = __half2float(alpha[(size_t)(i + 1) * 8 + h]);
        float a2 = __half2float(alpha[(size_t)(i + 2) * 8 + h]);
        float a3 = __half2float(alpha[(size_t)(i + 3) * 8 + h]);
        uint2 v0 = hv[(size_t)s0 * 64 + lane];
        uint2 v1 = hv[(size_t)s1 * 64 + lane];
        uint2 v2 = hv[(size_t)s2 * 64 + lane];
        uint2 v3 = hv[(size_t)s3 * 64 + lane];
        acc0 = fmaf(a0, bflo(v0.x), acc0);
        acc1 = fmaf(a0, bfhi(v0.x), acc1);
        acc2 = fmaf(a0, bflo(v0.y), acc2);
        acc3 = fmaf(a0, bfhi(v0.y), acc3);
        acc0 = fmaf(a1, bflo(v1.x), acc0);
        acc1 = fmaf(a1, bfhi(v1.x), acc1);
        acc2 = fmaf(a1, bflo(v1.y), acc2);
        acc3 = fmaf(a1, bfhi(v1.y), acc3);
        acc0 = fmaf(a2, bflo(v2.x), acc0);
        acc1 = fmaf(a2, bfhi(v2.x), acc1);
        acc2 = fmaf(a2, bflo(v2.y), acc2);
        acc3 = fmaf(a2, bfhi(v2.y), acc3);
        acc0 = fmaf(a3, bflo(v3.x), acc0);
        acc1 = fmaf(a3, bfhi(v3.x), acc1);
        acc2 = fmaf(a3, bflo(v3.y), acc2);
        acc3 = fmaf(a3, bfhi(v3.y), acc3);
    }
    for (; i < end; i++) {
        int s0 = csr[i];
        float a0 = __half2float(alpha[(size_t)i * 8 + h]);
        uint2 v0 = hv[(size_t)s0 * 64 + lane];
        acc0 = fmaf(a0, bflo(v0.x), acc0);
        acc1 = fmaf(a0, bfhi(v0.x), acc1);
        acc2 = fmaf(a0, bflo(v0.y), acc2);
        acc3 = fmaf(a0, bfhi(v0.y), acc3);
    }
    int c0 = 4 * lane;
    float4 bv = *((const float4*)(b1 + c0));
    float o0 = fmaxf(acc0 + bv.x, 0.f);
    float o1 = fmaxf(acc1 + bv.y, 0.f);
    float o2 = fmaxf(acc2 + bv.z, 0.f);
    float o3 = fmaxf(acc3 + bv.w, 0.f);
    uint lo = (uint)f2bf(o0) | ((uint)f2bf(o1) << 16);
    uint hi = (uint)f2bf(o2) | ((uint)f2bf(o3) << 16);
    ((uint2*)hrb)[(size_t)n * 64 + lane] = make_uint2(lo, hi);   // + b1, ReLU
}

// ---------------- Layer 2 GEMM: MFMA on bf16 hr, split-bf16 W2 ----------------
// 1 row-tile (16 rows) / wave; h2 + scores fused.

__global__ __launch_bounds__(256) void gemm2m_k(
        const ushort* __restrict__ hrb, const ushort* __restrict__ W2b,
        const ushort* __restrict__ W2r, const float* __restrict__ a2s,
        const float* __restrict__ a2d, ushort* __restrict__ h2u,
        float* __restrict__ s2s, float* __restrict__ s2d) {
    int lane = threadIdx.x & 63, wv = threadIdx.x >> 6;
    int rt = blockIdx.x * 4 + wv;
    if (rt >= N_RT) return;
    int r = lane & 15, g = lane >> 4;
    int row = rt * 16 + r;
    const ushort* arow = hrb + (size_t)row * 256;

    v8s af[8];
    #pragma unroll
    for (int ks = 0; ks < 8; ks++) {
        uint2 u0 = *((const uint2*)(arow + ks * 32 + g * 4));
        uint2 u1 = *((const uint2*)(arow + ks * 32 + 16 + g * 4));
        uint4 p; p.x = u0.x; p.y = u0.y; p.z = u1.x; p.w = u1.y;
        af[ks] = *((v8s*)&p);
    }

    f32x4 acc[2];
    acc[0] = (f32x4){0.f, 0.f, 0.f, 0.f};
    acc[1] = (f32x4){0.f, 0.f, 0.f, 0.f};
    const v8s* wbp = (const v8s*)W2b;
    const v8s* wrp = (const v8s*)W2r;
    #pragma unroll
    for (int ks = 0; ks < 8; ks++) {
        #pragma unroll
        for (int ct = 0; ct < 2; ct++) {
            v8s wb = wbp[(ct * 8 + ks) * 64 + lane];
            v8s wr = wrp[(ct * 8 + ks) * 64 + lane];
            acc[ct] = __builtin_amdgcn_mfma_f32_16x16x32_bf16(wb, af[ks], acc[ct], 0, 0, 0);
            acc[ct] = __builtin_amdgcn_mfma_f32_16x16x32_bf16(wr, af[ks], acc[ct], 0, 0, 0);
        }
    }

    float ps = 0.f, pd = 0.f;
    #pragma unroll
    for (int ct = 0; ct < 2; ct++) {
        #pragma unroll
        for (int q = 0; q < 4; q++) {
            int c = ct * 16 + g * 4 + q;
            ps = fmaf(acc[ct][q], a2s[c], ps);
            pd = fmaf(acc[ct][q], a2d[c], pd);
        }
    }
    ps += __shfl_xor(ps, 16); ps += __shfl_xor(ps, 32);
    pd += __shfl_xor(pd, 16); pd += __shfl_xor(pd, 32);
    if (g == 0) { s2s[row] = ps; s2d[row] = pd; }

    #pragma unroll
    for (int ct = 0; ct < 2; ct++) {
        uint lo = (uint)f2bf(acc[ct][0]) | ((uint)f2bf(acc[ct][1]) << 16);
        uint hi = (uint)f2bf(acc[ct][2]) | ((uint)f2bf(acc[ct][3]) << 16);
        *((uint2*)(h2u + (size_t)row * 32 + ct * 16 + g * 4)) = make_uint2(lo, hi);
    }
}

// ---------------- Layer 2: FUSED stats + parallel gather ----------------
// 1 node / wave. Stats: 64-edge parallel + butterfly. Gather: 64-edge
// superchunks of lane-parallel alpha; 4 edges x 16 lanes concurrent FMA.

__global__ __launch_bounds__(256) void agg2_k(
        const int* __restrict__ csr, const int* __restrict__ offs,
        const ushort* __restrict__ h2u, const float* __restrict__ s2s,
        const float* __restrict__ s2d, const float* __restrict__ b2,
        float* __restrict__ out) {
    int lane = threadIdx.x & 63;
    int n = blockIdx.x * 4 + (threadIdx.x >> 6);   // grid exact: 12500*4
    int beg = offs[n], end = offs[n + 1];
    float sd = s2d[n];

    float m = -3.4e38f, dd = 0.f;
    for (int i = beg + lane; i < end; i += 64) {
        float e = s2s[csr[i]] + sd;
        e = (e >= 0.f) ? e : 0.2f * e;
        float mn = fmaxf(m, e);
        dd = dd * __expf(m - mn) + __expf(e - mn);
        m = mn;
    }
    #pragma unroll
    for (int mask = 1; mask <= 32; mask <<= 1) {
        float om = __shfl_xor(m, mask);
        float od = __shfl_xor(dd, mask);
        float nm = fmaxf(m, om);
        dd = dd * __expf(m - nm) + od * __expf(om - nm);
        m = nm;
    }
    float inv = 1.f / (dd + 1e-16f);

    int e4 = lane >> 4, cp = lane & 15;            // edge-slot, channel-pair
    float acc0 = 0.f, acc1 = 0.f;
    for (int c0 = beg; c0 < end; c0 += 64) {
        int i = c0 + lane;
        int sL = 0; float aL = 0.f;
        if (i < end) {
            sL = csr[i];
            float e = s2s[sL] + sd;
            e = (e >= 0.f) ? e : 0.2f * e;
            aL = __expf(e - m) * inv;
        }
        int nsub = min(64, end - c0);               // wave-uniform
        for (int el = 0; el < nsub; el += 4) {
            int local = el + e4;
            int se = __shfl(sL, local);
            float ae = __shfl(aL, local);
            uint v = *((const uint*)(h2u + (size_t)se * 32 + cp * 2));
            acc0 = fmaf(ae, bflo(v), acc0);
            acc1 = fmaf(ae, bfhi(v), acc1);
        }
    }
    acc0 += __shfl_xor(acc0, 16); acc0 += __shfl_xor(acc0, 32);
    acc1 += __shfl_xor(acc1, 16); acc1 += __shfl_xor(acc1, 32);
    if (lane < 16) {
        float2 bv = ((const float2*)b2)[cp];
        float2 o; o.x = acc0 + bv.x; o.y = acc1 + bv.y;
        ((float2*)(out + (size_t)n * 32))[cp] = o;
    }
}

// ---------------- launch ----------------

extern "C" void kernel_launch(void* const* d_in, const int* in_sizes, int n_in,
                              void* d_out, int out_size, void* d_ws, size_t ws_size,
                              hipStream_t stream) {
    const float* x   = (const float*)d_in[0];
    const int*   ei  = (const int*)d_in[1];
    const float* W1  = (const float*)d_in[2];
    const float* a1s = (const float*)d_in[3];
    const float* a1d = (const float*)d_in[4];
    const float* b1  = (const float*)d_in[5];
    const float* W2  = (const float*)d_in[6];
    const float* a2s = (const float*)d_in[7];
    const float* a2d = (const float*)d_in[8];
    const float* b2  = (const float*)d_in[9];
    float* out = (float*)d_out;

    char* w = (char*)d_ws;
    ushort* h1u   = (ushort*)w; w += (size_t)N_NODES * 256 * 2;
    ushort* hrb   = (ushort*)w; w += (size_t)N_NODES * 256 * 2;
    ushort* W1f   = (ushort*)w; w += (size_t)16 * 4 * 64 * 8 * 2;
    ushort* Abf   = (ushort*)w; w += (size_t)4 * 64 * 8 * 2;
    ushort* Arf   = (ushort*)w; w += (size_t)4 * 64 * 8 * 2;
    ushort* W2b   = (ushort*)w; w += (size_t)2 * 8 * 64 * 8 * 2;
    ushort* W2r   = (ushort*)w; w += (size_t)2 * 8 * 64 * 8 * 2;
    ushort* h2u   = (ushort*)w; w += (size_t)N_NODES * 32 * 2;
    float* s1s    = (float*)w;  w += (size_t)N_NODES * 8 * 4;
    float* s1d    = (float*)w;  w += (size_t)N_NODES * 8 * 4;
    float* s2s    = (float*)w;  w += (size_t)N_NODES * 4;
    float* s2d    = (float*)w;  w += (size_t)N_NODES * 4;
    __half* alpha = (__half*)w; w += (size_t)E_TOT * 8 * 2;
    int* cnt    = (int*)w; w += (size_t)N_NODES * 4;
    int* offs   = (int*)w; w += (size_t)(N_NODES + 1) * 4;
    int* cursor = (int*)w; w += (size_t)(N_NODES + 4) * 4;
    int* bsum   = (int*)w; w += (size_t)NB_SCAN * 4;
    int* csr    = (int*)w; w += (size_t)E_TOT * 4;

    wprep_k<<<21, 256, 0, stream>>>(W1, a1s, a1d, W2, W1f, W2b, W2r, Abf, Arf, cnt);
    hist_k<<<(E_TOT + 255) / 256, 256, 0, stream>>>(ei, cnt);
    scanA_k<<<NB_SCAN, 256, 0, stream>>>(cnt, offs, bsum);
    scanC_k<<<NB_SCAN, 256, 0, stream>>>(bsum, offs, cursor);
    scat_k<<<(E_TOT + 255) / 256, 256, 0, stream>>>(ei, cursor, csr);

    fgemm1_k<<<(N_RT + 3) / 4, 256, 0, stream>>>(x, W1f, Abf, Arf, h1u, s1s, s1d);
    stats1_k<<<N_NODES / 4, 256, 0, stream>>>(csr, offs, s1s, s1d, alpha);
    agg1_k<<<N_NODES / 4, 256, 0, stream>>>(csr, offs, h1u, alpha, b1, hrb);
    gemm2m_k<<<(N_RT + 3) / 4, 256, 0, stream>>>(hrb, W2b, W2r, a2s, a2d, h2u, s2s, s2d);
    agg2_k<<<N_NODES / 4, 256, 0, stream>>>(csr, offs, h2u, s2s, s2d, b2, out);
}